// Round 1
// 321.156 us; speedup vs baseline: 1.0717x; 1.0717x over previous
//
#include <hip/hip_runtime.h>
#include <hip/hip_bf16.h>
#include <math.h>

// ---- problem constants ----
#define B_ 2
#define L_ 1024
#define HID_ 1536
#define NH_ 24
#define HD_ 64
#define DSSM_ 1536
#define QKV_ 4608
#define M_ 2048

typedef __attribute__((ext_vector_type(8))) short short8;
typedef __attribute__((ext_vector_type(4))) float floatx4;

// async global -> LDS, 16 bytes per lane (global_load_lds_dwordx4)
__device__ __forceinline__ void gload_lds16(const short* g, short* l)
{
    __builtin_amdgcn_global_load_lds(
        (const __attribute__((address_space(1))) void*)g,
        (__attribute__((address_space(3))) void*)l,
        16, 0, 0);
}

__device__ __forceinline__ float bfs2f(short s)
{
    unsigned u = ((unsigned)(unsigned short)s) << 16;
    float f; __builtin_memcpy(&f, &u, 4); return f;
}
__device__ __forceinline__ short f2bfs(float f)
{
    __hip_bfloat16 h = __float2bfloat16(f);
    short s; __builtin_memcpy(&s, &h, 2); return s;
}

// (it, slice) lookup for the 30 slice-blocks per (b,nh)
__device__ const int kIt[30] = {0,1,2,3,4,5, 6,6, 7,7, 8,8, 9,9, 10,10, 11,11,
                                12,12,12, 13,13,13, 14,14,14, 15,15,15};
__device__ const int kS[30]  = {0,0,0,0,0,0, 0,1, 0,1, 0,1, 0,1, 0,1, 0,1,
                                0,1,2, 0,1,2, 0,1,2, 0,1,2};

// =====================================================================
// fused fp32 -> bf16 cast for x, w_qkv, w_z (contiguous into wcat), w_o
// =====================================================================
#define CN0 (M_ * HID_)       // 3,145,728
#define CN1 (QKV_ * HID_)     // 7,077,888
#define CN2 (DSSM_ * HID_)    // 2,359,296
#define CN3 (HID_ * DSSM_)    // 2,359,296
__global__ void cast_all_kernel(
    const float* __restrict__ x,  const float* __restrict__ wq,
    const float* __restrict__ wz, const float* __restrict__ wo,
    __hip_bfloat16* __restrict__ xb,
    __hip_bfloat16* __restrict__ wcat,   // [QKV+DSSM, HID]
    __hip_bfloat16* __restrict__ wob)
{
    int i = (blockIdx.x * 256 + threadIdx.x) * 4;
    const float* src; __hip_bfloat16* dst; int off;
    if (i < CN0)                   { src = x;  dst = xb;         off = i; }
    else if (i < CN0 + CN1)        { src = wq; dst = wcat;       off = i - CN0; }
    else if (i < CN0 + CN1 + CN2)  { src = wz; dst = wcat + CN1; off = i - CN0 - CN1; }
    else                           { src = wo; dst = wob;        off = i - CN0 - CN1 - CN2; }
    float4 f = *reinterpret_cast<const float4*>(src + off);
    dst[off]     = __float2bfloat16(f.x);
    dst[off + 1] = __float2bfloat16(f.y);
    dst[off + 2] = __float2bfloat16(f.z);
    dst[off + 3] = __float2bfloat16(f.w);
}

// =====================================================================
// Fused qkv+z GEMM, 256x256 tile / BK=64 / 8 waves, 4-phase counted-vmcnt
// pipeline (T2 swizzle + T3 phases + T4 counted vmcnt + T5 setprio).
// C[M, 6144] = xb[M,K] @ wcat[6144,K]^T
// cols < QKV -> bf16 qkv_out; cols >= QKV -> fp32 + b_z -> z_out.
// grid 24x8 = 192 blocks, 512 threads, 128 KiB dynamic LDS.
//
// LDS layout (shorts): A buf c at c*16384, B buf c at 32768 + c*16384.
// Tile stored [256 rows][64 k] with byte-swizzle  off ^= ((row&7)<<4)
// applied identically on the global SOURCE of global_load_lds (linear
// LDS dest) and on the ds_read offsets (both-sides involution).
//
// Stage stream (1 half = 128 rows x 64 k = 2 loads/thread), per tile t:
//   ph1: B(t+1)h0   ph2: B(t+1)h1   ph3: A(t+2)h0   ph4: A(t+2)h1
// Liveness: A(cur) last read ph2 (kk1 frags) -> A staged-over ph3/4 OK;
// B(cur) last read ph3 -> B(t+2) staged tile t+1 ph1 OK (barrier between).
// vmcnt(4) at ph4 leaves only A(t+2) (4 loads) in flight => tile t+1
// fully resident before its ph1 reads.  Last 2 tiles drain vmcnt(0).
// =====================================================================
#define MFMA_ __builtin_amdgcn_mfma_f32_16x16x32_bf16
#define BAR_() __builtin_amdgcn_s_barrier()
#define DRAIN_() do { asm volatile("s_waitcnt lgkmcnt(0)" ::: "memory"); \
                      __builtin_amdgcn_sched_barrier(0); } while (0)

__global__ __launch_bounds__(512, 2) void gemm_qkvz_256(
    const __hip_bfloat16* __restrict__ A,
    const __hip_bfloat16* __restrict__ Bm,
    __hip_bfloat16* __restrict__ qkv_out,
    float* __restrict__ z_out,
    const float* __restrict__ b_z)
{
    extern __shared__ short lds[];
    const int K  = HID_;
    const int NT = K / 64;                 // 24 K-tiles
    const int tid   = threadIdx.x;
    const int lane  = tid & 63;
    const int wave  = tid >> 6;
    const int col16 = lane & 15;
    const int quad  = lane >> 4;
    const int wm = wave >> 2;              // 0..1  (M half)
    const int wn = wave & 3;               // 0..3  (N quarter)
    const int rowblk = blockIdx.y * 256;
    const int colblk = blockIdx.x * 256;

    const short* Ap = reinterpret_cast<const short*>(A);
    const short* Bp = reinterpret_cast<const short*>(Bm);

    // staging source mapping (inverse swizzle; constant per thread)
    const int o  = tid * 16;                         // byte off in 16KB half
    const int s  = o ^ (((o >> 7) & 7) << 4);
    const int sr = s >> 7;                           // row 0..63 within half
    const int sc = (s & 127) >> 1;                   // short col 0..63
    const int ldst = tid * 8;                        // dest short idx in half

    // read-side swizzled k-offsets (shorts)
    const int mask = (col16 & 7) << 4;               // byte swizzle mask
    const int e0 = ((quad * 16)      ^ mask) >> 1;   // kk=0
    const int e1 = ((64 + quad * 16) ^ mask) >> 1;   // kk=1
    const int arow = (wm * 128 + col16) * 64;        // + m*1024
    const int brow = (wn * 64  + col16) * 64;        // + n*1024

    floatx4 acc[8][4] = {};

    auto STAGE_A = [&](int c, int h, int t) {
        const short* g = Ap + (size_t)(rowblk + h * 128 + sr) * K + t * 64 + sc;
        short* d = &lds[c * 16384 + h * 8192 + ldst];
        gload_lds16(g, d);
        gload_lds16(g + (size_t)64 * K, d + 4096);
    };
    auto STAGE_B = [&](int c, int h, int t) {
        const short* g = Bp + (size_t)(colblk + h * 128 + sr) * K + t * 64 + sc;
        short* d = &lds[32768 + c * 16384 + h * 8192 + ldst];
        gload_lds16(g, d);
        gload_lds16(g + (size_t)64 * K, d + 4096);
    };

    // ---- prologue: tile0 complete + tile1 A; allow tile1 A in flight ----
    STAGE_A(0, 0, 0); STAGE_A(0, 1, 0);
    STAGE_B(0, 0, 0); STAGE_B(0, 1, 0);
    STAGE_A(1, 0, 1); STAGE_A(1, 1, 1);
    asm volatile("s_waitcnt vmcnt(4)" ::: "memory");
    __builtin_amdgcn_sched_barrier(0);
    BAR_();

    for (int t = 0; t < NT; ++t) {
        const int cur = t & 1, nxt = cur ^ 1;
        const int Ab = cur * 16384;
        const int Bb = 32768 + cur * 16384;
        short8 af0[8], af1[8], bf0[4], bf1[4];

        // ---- phase 1: read A kk0 + B kk0; stage B(t+1)h0; MFMA kk0 n0,1
#pragma unroll
        for (int m = 0; m < 8; ++m)
            af0[m] = *reinterpret_cast<const short8*>(&lds[Ab + arow + m * 1024 + e0]);
#pragma unroll
        for (int n = 0; n < 4; ++n)
            bf0[n] = *reinterpret_cast<const short8*>(&lds[Bb + brow + n * 1024 + e0]);
        if (t + 1 < NT) STAGE_B(nxt, 0, t + 1);
        BAR_();
        __builtin_amdgcn_s_setprio(1);
#pragma unroll
        for (int m = 0; m < 8; ++m) {
            acc[m][0] = MFMA_(af0[m], bf0[0], acc[m][0], 0, 0, 0);
            acc[m][1] = MFMA_(af0[m], bf0[1], acc[m][1], 0, 0, 0);
        }
        __builtin_amdgcn_s_setprio(0);
        DRAIN_();
        BAR_();

        // ---- phase 2: read A kk1; stage B(t+1)h1; MFMA kk0 n2,3
#pragma unroll
        for (int m = 0; m < 8; ++m)
            af1[m] = *reinterpret_cast<const short8*>(&lds[Ab + arow + m * 1024 + e1]);
        if (t + 1 < NT) STAGE_B(nxt, 1, t + 1);
        BAR_();
        __builtin_amdgcn_s_setprio(1);
#pragma unroll
        for (int m = 0; m < 8; ++m) {
            acc[m][2] = MFMA_(af0[m], bf0[2], acc[m][2], 0, 0, 0);
            acc[m][3] = MFMA_(af0[m], bf0[3], acc[m][3], 0, 0, 0);
        }
        __builtin_amdgcn_s_setprio(0);
        DRAIN_();
        BAR_();

        // ---- phase 3: read B kk1; stage A(t+2)h0; MFMA kk1 n0,1
#pragma unroll
        for (int n = 0; n < 4; ++n)
            bf1[n] = *reinterpret_cast<const short8*>(&lds[Bb + brow + n * 1024 + e1]);
        if (t + 2 < NT) STAGE_A(cur, 0, t + 2);
        BAR_();
        __builtin_amdgcn_s_setprio(1);
#pragma unroll
        for (int m = 0; m < 8; ++m) {
            acc[m][0] = MFMA_(af1[m], bf1[0], acc[m][0], 0, 0, 0);
            acc[m][1] = MFMA_(af1[m], bf1[1], acc[m][1], 0, 0, 0);
        }
        __builtin_amdgcn_s_setprio(0);
        DRAIN_();
        BAR_();

        // ---- phase 4: stage A(t+2)h1; counted vmcnt; MFMA kk1 n2,3
        if (t + 2 < NT) STAGE_A(cur, 1, t + 2);
        if (t >= NT - 2) { asm volatile("s_waitcnt vmcnt(0)" ::: "memory"); }
        else             { asm volatile("s_waitcnt vmcnt(4)" ::: "memory"); }
        __builtin_amdgcn_sched_barrier(0);
        BAR_();
        __builtin_amdgcn_s_setprio(1);
#pragma unroll
        for (int m = 0; m < 8; ++m) {
            acc[m][2] = MFMA_(af1[m], bf1[2], acc[m][2], 0, 0, 0);
            acc[m][3] = MFMA_(af1[m], bf1[3], acc[m][3], 0, 0, 0);
        }
        __builtin_amdgcn_s_setprio(0);
        DRAIN_();
        BAR_();
    }

    // ---- epilogue ----
    const int row0  = rowblk + wm * 128;
    const int col0g = colblk + wn * 64;
    if (colblk < QKV_) {
#pragma unroll
        for (int m = 0; m < 8; ++m)
#pragma unroll
            for (int n = 0; n < 4; ++n)
#pragma unroll
                for (int r = 0; r < 4; ++r) {
                    int row = row0 + m * 16 + quad * 4 + r;
                    int col = col0g + n * 16 + col16;
                    qkv_out[(size_t)row * QKV_ + col] = __float2bfloat16(acc[m][n][r]);
                }
    } else {
#pragma unroll
        for (int m = 0; m < 8; ++m)
#pragma unroll
            for (int n = 0; n < 4; ++n)
#pragma unroll
                for (int r = 0; r < 4; ++r) {
                    int row = row0 + m * 16 + quad * 4 + r;
                    int col = col0g + n * 16 + col16 - QKV_;
                    z_out[(size_t)row * DSSM_ + col] = acc[m][n][r] + b_z[col];
                }
    }
}

// =====================================================================
// NT GEMM, LDS-staged (m97 structure) — used for the output projection
// =====================================================================
template<int OUTMODE>
__global__ __launch_bounds__(256) void gemm_nt(
    const __hip_bfloat16* __restrict__ A,
    const __hip_bfloat16* __restrict__ Bm,
    void* __restrict__ Cv,
    const float* __restrict__ bias,
    int M, int N, int K)
{
    const int lane  = threadIdx.x & 63;
    const int wave  = threadIdx.x >> 6;
    const int col16 = lane & 15;
    const int quad  = lane >> 4;
    const int wr    = wave >> 1;
    const int wc    = wave & 1;
    const int rowblk = blockIdx.y * 128;
    const int colblk = blockIdx.x * 128;

    const short* Ap = reinterpret_cast<const short*>(A);
    const short* Bp = reinterpret_cast<const short*>(Bm);

    __shared__ alignas(16) short As[128 * 32];
    __shared__ alignas(16) short Bs[128 * 32];

    const int srow = lane >> 2;
    const int scol = (lane & 3) * 8;

    floatx4 acc[4][4] = {};

    for (int k0 = 0; k0 < K; k0 += 32) {
#pragma unroll
        for (int s2 = 0; s2 < 2; ++s2) {
            const int seg = wave * 2 + s2;
            gload_lds16(Ap + (size_t)(rowblk + seg * 16 + srow) * K + k0 + scol,
                        &As[seg * 512]);
            gload_lds16(Bp + (size_t)(colblk + seg * 16 + srow) * K + k0 + scol,
                        &Bs[seg * 512]);
        }
        __syncthreads();

        short8 af[4], bf[4];
#pragma unroll
        for (int t = 0; t < 4; ++t) {
            af[t] = *reinterpret_cast<const short8*>(
                &As[(wr * 64 + t * 16 + col16) * 32 + quad * 8]);
            bf[t] = *reinterpret_cast<const short8*>(
                &Bs[(wc * 64 + t * 16 + col16) * 32 + quad * 8]);
        }
#pragma unroll
        for (int mt = 0; mt < 4; ++mt)
#pragma unroll
            for (int nt = 0; nt < 4; ++nt)
                acc[mt][nt] = __builtin_amdgcn_mfma_f32_16x16x32_bf16(
                    af[mt], bf[nt], acc[mt][nt], 0, 0, 0);
        __syncthreads();
    }

    const int row0 = rowblk + wr * 64;
    const int col0 = colblk + wc * 64;
#pragma unroll
    for (int mt = 0; mt < 4; ++mt) {
#pragma unroll
        for (int nt = 0; nt < 4; ++nt) {
#pragma unroll
            for (int r = 0; r < 4; ++r) {
                int row = row0 + mt * 16 + quad * 4 + r;
                int col = col0 + nt * 16 + col16;
                float v = acc[mt][nt][r];
                if (OUTMODE == 1) v += bias[col];
                if (OUTMODE == 2)
                    ((__hip_bfloat16*)Cv)[(size_t)row * N + col] = __float2bfloat16(v);
                else
                    ((float*)Cv)[(size_t)row * N + col] = v;
            }
        }
    }
}

// =====================================================================
// depthwise causal conv (k=2) + SiLU -> q/k/v [B,NH,L,HD] bf16
// =====================================================================
__global__ void conv_silu_kernel(
    const __hip_bfloat16* __restrict__ raw,
    const float* __restrict__ conv_w,
    __hip_bfloat16* __restrict__ q,
    __hip_bfloat16* __restrict__ k,
    __hip_bfloat16* __restrict__ v)
{
    int idx = blockIdx.x * 256 + threadIdx.x;   // over B*L*QKV
    int c  = idx % QKV_;
    int ml = idx / QKV_;
    int l  = ml % L_;

    float cur  = __bfloat162float(raw[idx]);
    float prev = (l > 0) ? __bfloat162float(raw[idx - QKV_]) : 0.f;
    float u = prev * conv_w[c * 2] + cur * conv_w[c * 2 + 1];
    u = fmaxf(u, -80.f);
    float s = u / (1.f + __expf(-u));           // silu

    int part = c / DSSM_;
    int cc   = c % DSSM_;
    int nh   = cc >> 6;
    int d    = cc & 63;
    int b    = ml / L_;
    __hip_bfloat16* dst = (part == 0) ? q : ((part == 1) ? k : v);
    dst[(((size_t)b * NH_ + nh) * L_ + l) * HD_ + d] = __float2bfloat16(s);
}

// =====================================================================
// dt projection v2 (fp32, LDS-staged x, register-held fragments)
// =====================================================================
__global__ __launch_bounds__(256) void dtproj_kernel(
    const float* __restrict__ x,        // [B*L, HID]
    const float* __restrict__ w_dt,     // [NH, HID]
    const float* __restrict__ dt_bias,  // [NH]
    const float* __restrict__ a_log,    // [NH]
    float* __restrict__ dt,             // [B*NH, L]
    float* __restrict__ dA)
{
    const int m0   = blockIdx.x * 8;
    const int tid  = threadIdx.x;
    const int wave = tid >> 6;
    const int lane = tid & 63;

    __shared__ float Xs[8][HID_];

    for (int t = tid; t < 8 * (HID_ / 4); t += 256) {
        int r = t / (HID_ / 4), c = (t % (HID_ / 4)) * 4;
        *reinterpret_cast<float4*>(&Xs[r][c]) =
            *reinterpret_cast<const float4*>(x + (size_t)(m0 + r) * HID_ + c);
    }
    __syncthreads();

    const int r0 = wave * 2;
    float4 xa[2][6];
#pragma unroll
    for (int rr = 0; rr < 2; ++rr)
#pragma unroll
        for (int it = 0; it < 6; ++it)
            xa[rr][it] = *reinterpret_cast<const float4*>(&Xs[r0 + rr][lane * 4 + it * 256]);

    for (int n = 0; n < NH_; ++n) {
        float s0 = 0.f, s1 = 0.f;
#pragma unroll
        for (int it = 0; it < 6; ++it) {
            float4 w = *reinterpret_cast<const float4*>(
                w_dt + (size_t)n * HID_ + lane * 4 + it * 256);
            s0 += xa[0][it].x * w.x + xa[0][it].y * w.y
                + xa[0][it].z * w.z + xa[0][it].w * w.w;
            s1 += xa[1][it].x * w.x + xa[1][it].y * w.y
                + xa[1][it].z * w.z + xa[1][it].w * w.w;
        }
#pragma unroll
        for (int off = 32; off; off >>= 1) {
            s0 += __shfl_xor(s0, off, 64);
            s1 += __shfl_xor(s1, off, 64);
        }
        if (lane == 0) {
            float Aval = -__expf(a_log[n]);
            float bias = dt_bias[n];
#pragma unroll
            for (int rr = 0; rr < 2; ++rr) {
                float vdt = (rr == 0 ? s0 : s1) + bias;
                vdt = (vdt > 20.f) ? vdt : log1pf(__expf(vdt));
                int m = m0 + r0 + rr;
                int b = m / L_, l = m % L_;
                size_t o = ((size_t)b * NH_ + n) * L_ + l;
                dt[o] = vdt;
                dA[o] = vdt * Aval;
            }
        }
    }
}

// =====================================================================
// cumsum over L per (b,nh)
// =====================================================================
__global__ void cumsum_kernel(const float* __restrict__ dA, float* __restrict__ cs)
{
    int bnh  = blockIdx.x;
    int lane = threadIdx.x;
    const float* src = dA + (size_t)bnh * L_;
    float* dst       = cs + (size_t)bnh * L_;

    float loc[16];
    float run = 0.f;
#pragma unroll
    for (int t = 0; t < 16; ++t) { run += src[lane * 16 + t]; loc[t] = run; }
    float tot = run;
    float sc = tot;
#pragma unroll
    for (int off = 1; off < 64; off <<= 1) {
        float o = __shfl_up(sc, off, 64);
        if (lane >= off) sc += o;
    }
    float offset = sc - tot;
#pragma unroll
    for (int t = 0; t < 16; ++t) dst[lane * 16 + t] = loc[t] + offset;
}

// =====================================================================
// V -> Vt transpose with dt folding
// =====================================================================
__global__ __launch_bounds__(256) void vdt_transpose_kernel(
    const __hip_bfloat16* __restrict__ v,   // [B,NH,L,HD]
    const float* __restrict__ dt,           // [B,NH,L]
    __hip_bfloat16* __restrict__ vt)        // [B,NH,HD,L] (dt-scaled)
{
    const int lt0 = blockIdx.x * 64;
    const int bnh = blockIdx.z * NH_ + blockIdx.y;
    const int tid = threadIdx.x;

    __shared__ short T[64][72];

    {
        int row = tid >> 2;
        int cc  = (tid & 3) * 16;
        const short* sp = reinterpret_cast<const short*>(v)
                        + ((size_t)bnh * L_ + lt0 + row) * HD_ + cc;
        float dtr = dt[(size_t)bnh * L_ + lt0 + row];
        short8 a = *reinterpret_cast<const short8*>(sp);
        short8 b = *reinterpret_cast<const short8*>(sp + 8);
#pragma unroll
        for (int j = 0; j < 8; ++j) {
            T[row][cc + j]     = f2bfs(bfs2f(a[j]) * dtr);
            T[row][cc + 8 + j] = f2bfs(bfs2f(b[j]) * dtr);
        }
    }
    __syncthreads();
    {
        int d  = tid >> 2;
        int lc = (tid & 3) * 16;
        short8 o0, o1;
#pragma unroll
        for (int j = 0; j < 8; ++j) {
            o0[j] = T[lc + j][d];
            o1[j] = T[lc + 8 + j][d];
        }
        short* dst = reinterpret_cast<short*>(vt)
                   + ((size_t)bnh * HD_ + d) * L_ + lt0 + lc;
        *reinterpret_cast<short8*>(dst)     = o0;
        *reinterpret_cast<short8*>(dst + 8) = o1;
    }
}

// =====================================================================
// quadratic SSD attention — one (i-tile, j-slice) per block.
// =====================================================================
__global__ __launch_bounds__(256) void attn_kernel(
    const __hip_bfloat16* __restrict__ q,   // [B,NH,L,HD]
    const __hip_bfloat16* __restrict__ k,   // [B,NH,L,HD]
    const __hip_bfloat16* __restrict__ vt,  // [B,NH,HD,L], dt-scaled
    const float* __restrict__ cs,           // [B,NH,L]
    float* __restrict__ p0,                 // [B,L,DSSM] partials
    float* __restrict__ p1,
    float* __restrict__ p2)
{
    const int pidx = blockIdx.x;            // 0..29
    const int it   = kIt[pidx];
    const int sl   = kS[pidx];
    const int nh   = blockIdx.y;
    const int b    = blockIdx.z;
    const int tid  = threadIdx.x;
    const int lane = tid & 63;
    const int wave = tid >> 6;
    const int col  = lane & 15;
    const int quad = lane >> 4;
    const int bnh  = b * NH_ + nh;
    const int iw0  = it * 64 + wave * 16;

    float* pout = (sl == 0) ? p0 : ((sl == 1) ? p1 : p2);

    const short* qp  = reinterpret_cast<const short*>(q);
    const short* kp  = reinterpret_cast<const short*>(k);
    const short* vtp = reinterpret_cast<const short*>(vt);

    __shared__ alignas(16) short Ks[4096];
    __shared__ alignas(16) short Ps[4 * 16 * 72];

    const short* qrow = qp + ((size_t)bnh * L_ + iw0 + col) * HD_;
    short8 aq0 = *reinterpret_cast<const short8*>(qrow + quad * 8);
    short8 aq1 = *reinterpret_cast<const short8*>(qrow + 32 + quad * 8);

    float csr[4];
#pragma unroll
    for (int r = 0; r < 4; ++r)
        csr[r] = cs[(size_t)bnh * L_ + iw0 + quad * 4 + r];

    floatx4 accO[4] = {};

    const int jt_end = min(sl * 6 + 5, it);
    for (int jt = sl * 6; jt <= jt_end; ++jt) {
        const int j0 = jt * 64;
        {
            const short* gk = kp + ((size_t)bnh * L_ + j0 + wave * 16 + (lane >> 2)) * HD_
                            + (lane & 3) * 8;
            gload_lds16(gk,      &Ks[wave * 512 + lane * 8]);
            gload_lds16(gk + 32, &Ks[2048 + wave * 512 + lane * 8]);
        }
        __syncthreads();

#pragma unroll
        for (int s = 0; s < 4; ++s) {
            int jsub = j0 + s * 16;
            if (jsub <= iw0 + 15) {
                short8 bk0 = *reinterpret_cast<const short8*>(
                    &Ks[(s * 16 + col) * 32 + quad * 8]);
                short8 bk1 = *reinterpret_cast<const short8*>(
                    &Ks[2048 + (s * 16 + col) * 32 + quad * 8]);
                floatx4 sc = {};
                sc = __builtin_amdgcn_mfma_f32_16x16x32_bf16(aq0, bk0, sc, 0, 0, 0);
                sc = __builtin_amdgcn_mfma_f32_16x16x32_bf16(aq1, bk1, sc, 0, 0, 0);
                int j = jsub + col;
                float csj = cs[(size_t)bnh * L_ + j];
#pragma unroll
                for (int r = 0; r < 4; ++r) {
                    int i = iw0 + quad * 4 + r;
                    float e = (j <= i) ? __expf(csr[r] - csj) : 0.f;
                    Ps[wave * 1152 + (quad * 4 + r) * 72 + s * 16 + col] =
                        f2bfs(sc[r] * e);
                }
            } else if (j0 + (s >> 1) * 32 <= iw0 + 15) {
#pragma unroll
                for (int r = 0; r < 4; ++r)
                    Ps[wave * 1152 + (quad * 4 + r) * 72 + s * 16 + col] = 0;
            }
        }

#pragma unroll
        for (int c = 0; c < 2; ++c) {
            if (j0 + c * 32 > iw0 + 15) continue;
            short8 pa = *reinterpret_cast<const short8*>(
                &Ps[wave * 1152 + col * 72 + c * 32 + quad * 8]);
#pragma unroll
            for (int nt = 0; nt < 4; ++nt) {
                short8 bv = *reinterpret_cast<const short8*>(
                    vtp + ((size_t)bnh * HD_ + nt * 16 + col) * L_
                        + j0 + c * 32 + quad * 8);
                accO[nt] = __builtin_amdgcn_mfma_f32_16x16x32_bf16(pa, bv, accO[nt], 0, 0, 0);
            }
        }
        __syncthreads();
    }

#pragma unroll
    for (int nt = 0; nt < 4; ++nt) {
#pragma unroll
        for (int r = 0; r < 4; ++r) {
            int i  = iw0 + quad * 4 + r;
            int dv = nt * 16 + col;
            pout[((size_t)b * L_ + i) * DSSM_ + nh * HD_ + dv] = accO[nt][r];
        }
    }
}

// =====================================================================
// gate: (p0[+p1][+p2] + v*D) * silu(z), then RMSNorm * rms_w  -> bf16
// =====================================================================
__global__ __launch_bounds__(256) void gate_rms_kernel(
    const float* __restrict__ p0,
    const float* __restrict__ p1,
    const float* __restrict__ p2,
    const float* __restrict__ z,
    const __hip_bfloat16* __restrict__ v,   // [B,NH,L,HD]
    const float* __restrict__ Dm,           // [NH,HD]
    const float* __restrict__ rms_w,
    __hip_bfloat16* __restrict__ yn)
{
    int m   = blockIdx.x;           // b*L + l
    int b   = m / L_;
    int l   = m % L_;
    int tid = threadIdx.x;
    size_t base = (size_t)m * DSSM_;
    const bool has1 = (l >= 384);
    const bool has2 = (l >= 768);

    float g[6];
    float ss = 0.f;
#pragma unroll
    for (int t = 0; t < 6; ++t) {
        int c = tid + t * 256;
        int nh = c >> 6, d = c & 63;
        float vi = __bfloat162float(v[(((size_t)b * NH_ + nh) * L_ + l) * HD_ + d]);
        float yv = p0[base + c] + vi * Dm[c];
        if (has1) yv += p1[base + c];
        if (has2) yv += p2[base + c];
        float zv = fmaxf(z[base + c], -80.f);
        float gv = yv * (zv / (1.f + __expf(-zv)));
        g[t] = gv;
        ss += gv * gv;
    }
#pragma unroll
    for (int off = 32; off; off >>= 1) ss += __shfl_xor(ss, off, 64);
    __shared__ float red[4];
    if ((tid & 63) == 0) red[tid >> 6] = ss;
    __syncthreads();
    ss = red[0] + red[1] + red[2] + red[3];
    float r = rsqrtf(ss / (float)DSSM_ + 1e-6f);
#pragma unroll
    for (int t = 0; t < 6; ++t) {
        int c = tid + t * 256;
        yn[base + c] = __float2bfloat16(g[t] * r * rms_w[c]);
    }
}

// =====================================================================
extern "C" void kernel_launch(void* const* d_in, const int* in_sizes, int n_in,
                              void* d_out, int out_size, void* d_ws, size_t ws_size,
                              hipStream_t stream)
{
    const float* x       = (const float*)d_in[0];
    const float* w_qkv   = (const float*)d_in[1];
    const float* conv_w  = (const float*)d_in[2];
    const float* w_dt    = (const float*)d_in[3];
    const float* dt_bias = (const float*)d_in[4];
    const float* a_log   = (const float*)d_in[5];
    const float* Dm      = (const float*)d_in[6];
    const float* w_z     = (const float*)d_in[7];
    const float* b_z     = (const float*)d_in[8];
    const float* rms_w   = (const float*)d_in[9];
    const float* w_o     = (const float*)d_in[10];
    float* out = (float*)d_out;

    char* ws = (char*)d_ws;

    // ---- workspace layout (bytes), total 80,805,888 — overlap-audited ----
    // [0,         6291456)  : xb (cast->step1) -> vtb (5a->5b) -> yn (7->8)
    // [6291456,  11010048)  : wob (cast->step8, never reused)
    // [11010048, 23592960)  : zbuf fp32 (step1->step7)
    // [23592960, 61341696)  : wcat [23592960,42467328) + qkvb [42467328,61341696)
    //                         -> after step2 both dead -> p0|p1|p2 (3 x 12582912)
    // [61341696, 67633152)  : qb (step2->5b)
    // [67633152, 73924608)  : kb (step2->5b)
    // [73924608, 80216064)  : vb (step2->7)
    // [80216064, 80805888)  : dt | dA | cs
    __hip_bfloat16* xb    = (__hip_bfloat16*)(ws);
    __hip_bfloat16* wob   = (__hip_bfloat16*)(ws + 6291456);
    float*          zbuf  = (float*)(ws + 11010048);
    __hip_bfloat16* wcat  = (__hip_bfloat16*)(ws + 23592960);
    __hip_bfloat16* qkvb  = (__hip_bfloat16*)(ws + 42467328);
    __hip_bfloat16* qb    = (__hip_bfloat16*)(ws + 61341696);
    __hip_bfloat16* kb    = (__hip_bfloat16*)(ws + 67633152);
    __hip_bfloat16* vb    = (__hip_bfloat16*)(ws + 73924608);
    float* dt   = (float*)(ws + 80216064);
    float* dA   = (float*)(ws + 80412672);
    float* cs   = (float*)(ws + 80609280);
    // aliases (lifetimes disjoint per audit above)
    __hip_bfloat16* vtb = (__hip_bfloat16*)(ws);
    __hip_bfloat16* yn  = (__hip_bfloat16*)(ws);
    float* p0 = (float*)(ws + 23592960);
    float* p1 = (float*)(ws + 36175872);
    float* p2 = (float*)(ws + 48758784);

    // one-time: allow 128 KiB dynamic LDS for the 256^2 GEMM
    static bool attr_set = false;
    if (!attr_set) {
        (void)hipFuncSetAttribute(reinterpret_cast<const void*>(gemm_qkvz_256),
                                  hipFuncAttributeMaxDynamicSharedMemorySize,
                                  131072);
        attr_set = true;
    }

    // 0) fused casts: x->xb, w_qkv|w_z->wcat, w_o->wob
    cast_all_kernel<<<(CN0 + CN1 + CN2 + CN3) / 1024, 256, 0, stream>>>(
        x, w_qkv, w_z, w_o, xb, wcat, wob);

    // 1) fused qkv+z GEMM  [2048 x 6144], 256^2 tile 4-phase pipeline
    gemm_qkvz_256<<<dim3((QKV_ + DSSM_) / 256, M_ / 256), 512, 131072, stream>>>(
        xb, wcat, qkvb, zbuf, b_z);

    // 2) conv + silu -> q,k,v
    conv_silu_kernel<<<(B_ * L_ * QKV_) / 256, 256, 0, stream>>>(
        qkvb, conv_w, qb, kb, vb);

    // 3) dt / dA
    dtproj_kernel<<<M_ / 8, 256, 0, stream>>>(x, w_dt, dt_bias, a_log, dt, dA);

    // 4) cs = cumsum(dA)
    cumsum_kernel<<<B_ * NH_, 64, 0, stream>>>(dA, cs);

    // 5a) vt = transpose(v) * dt  (xb dead after step 1)
    vdt_transpose_kernel<<<dim3(L_ / 64, NH_, B_), 256, 0, stream>>>(vb, dt, vtb);

    // 5b) attention -> partials p0/p1/p2 (wcat+qkvb region dead)
    attn_kernel<<<dim3(30, NH_, B_), 256, 0, stream>>>(
        qb, kb, vtb, cs, p0, p1, p2);

    // 7) gate + RMSNorm -> yn (vtb slot; attn done)
    gate_rms_kernel<<<M_, 256, 0, stream>>>(p0, p1, p2, zbuf, vb, Dm, rms_w, yn);

    // 8) out = yn @ w_o^T
    gemm_nt<0><<<dim3(HID_ / 128, M_ / 128), 256, 0, stream>>>(
        yn, wob, (void*)out, nullptr, M_, HID_, DSSM_);
}

// Round 2
// 308.397 us; speedup vs baseline: 1.1161x; 1.0414x over previous
//
#include <hip/hip_runtime.h>
#include <hip/hip_bf16.h>
#include <math.h>

// ---- problem constants ----
#define B_ 2
#define L_ 1024
#define HID_ 1536
#define NH_ 24
#define HD_ 64
#define DSSM_ 1536
#define QKV_ 4608
#define M_ 2048

typedef __attribute__((ext_vector_type(8))) short short8;
typedef __attribute__((ext_vector_type(4))) short short4e;
typedef __attribute__((ext_vector_type(4))) float floatx4;

// async global -> LDS, 16 bytes per lane (global_load_lds_dwordx4)
__device__ __forceinline__ void gload_lds16(const short* g, short* l)
{
    __builtin_amdgcn_global_load_lds(
        (const __attribute__((address_space(1))) void*)g,
        (__attribute__((address_space(3))) void*)l,
        16, 0, 0);
}

__device__ __forceinline__ float bfs2f(short s)
{
    unsigned u = ((unsigned)(unsigned short)s) << 16;
    float f; __builtin_memcpy(&f, &u, 4); return f;
}
__device__ __forceinline__ short f2bfs(float f)
{
    __hip_bfloat16 h = __float2bfloat16(f);
    short s; __builtin_memcpy(&s, &h, 2); return s;
}

// (it, slice) lookup for the 30 slice-blocks per (b,nh)
__device__ const int kIt[30] = {0,1,2,3,4,5, 6,6, 7,7, 8,8, 9,9, 10,10, 11,11,
                                12,12,12, 13,13,13, 14,14,14, 15,15,15};
__device__ const int kS[30]  = {0,0,0,0,0,0, 0,1, 0,1, 0,1, 0,1, 0,1, 0,1,
                                0,1,2, 0,1,2, 0,1,2, 0,1,2};

// =====================================================================
// fused fp32 -> bf16 cast for x, w_qkv, w_z (contiguous into wcat), w_o
// =====================================================================
#define CN0 (M_ * HID_)       // 3,145,728
#define CN1 (QKV_ * HID_)     // 7,077,888
#define CN2 (DSSM_ * HID_)    // 2,359,296
#define CN3 (HID_ * DSSM_)    // 2,359,296
__global__ void cast_all_kernel(
    const float* __restrict__ x,  const float* __restrict__ wq,
    const float* __restrict__ wz, const float* __restrict__ wo,
    __hip_bfloat16* __restrict__ xb,
    __hip_bfloat16* __restrict__ wcat,   // [QKV+DSSM, HID]
    __hip_bfloat16* __restrict__ wob)
{
    int i = (blockIdx.x * 256 + threadIdx.x) * 4;
    const float* src; __hip_bfloat16* dst; int off;
    if (i < CN0)                   { src = x;  dst = xb;         off = i; }
    else if (i < CN0 + CN1)        { src = wq; dst = wcat;       off = i - CN0; }
    else if (i < CN0 + CN1 + CN2)  { src = wz; dst = wcat + CN1; off = i - CN0 - CN1; }
    else                           { src = wo; dst = wob;        off = i - CN0 - CN1 - CN2; }
    float4 f = *reinterpret_cast<const float4*>(src + off);
    dst[off]     = __float2bfloat16(f.x);
    dst[off + 1] = __float2bfloat16(f.y);
    dst[off + 2] = __float2bfloat16(f.z);
    dst[off + 3] = __float2bfloat16(f.w);
}

// =====================================================================
// Fused qkv+z GEMM, 256x192 tile / BK=64 / 8 waves, 3-phase counted-vmcnt
// pipeline.  grid 32x8 = 256 blocks = exactly 1/CU (was 192 -> 25% idle).
// C[M, 6144] = xb[M,K] @ wcat[6144,K]^T
// cols < QKV (blockIdx.x < 24) -> bf16 qkv_out via LDS-coalesced stores;
// cols >= QKV -> fp32 + b_z -> z_out direct.
//
// LDS (shorts): A buf c at c*16384 (256x64), B buf c at 32768 + c*12288
// (192x64).  Total 57344 shorts = 114,688 B.  Swizzle byte^=((row&7)<<4)
// applied on global SOURCE (linear LDS dest) and on ds_read offsets.
//
// Stage stream per tile t (7 units of 64 rows, 8KB = 512thr x 16B each):
//   ph1: B(t+1)u0,u1   ph2: B(t+1)u2   ph3: A(t+2)u0..u3
// Liveness: A(cur) last read ph2 (af1) -> A(t+2) staged ph3 after DRAIN+BAR.
// B(cur) last read ph3 start; B(t+2) staged tile t+1 ph1 (barrier between).
// vmcnt(4) at ph3 leaves only A(t+2) in flight => tile t+1 resident at ph1.
// Tail t>=NT-2: vmcnt(0).
// =====================================================================
#define MFMA_ __builtin_amdgcn_mfma_f32_16x16x32_bf16
#define BAR_() __builtin_amdgcn_s_barrier()
#define DRAIN_() do { asm volatile("s_waitcnt lgkmcnt(0)" ::: "memory"); \
                      __builtin_amdgcn_sched_barrier(0); } while (0)

#define CSTR 200   // epilogue C-LDS row stride (shorts): 400B, 16B-aligned

__global__ __launch_bounds__(512, 2) void gemm_qkvz_256(
    const __hip_bfloat16* __restrict__ A,
    const __hip_bfloat16* __restrict__ Bm,
    __hip_bfloat16* __restrict__ qkv_out,
    float* __restrict__ z_out,
    const float* __restrict__ b_z)
{
    extern __shared__ short lds[];
    const int K  = HID_;
    const int NT = K / 64;                 // 24 K-tiles
    const int tid   = threadIdx.x;
    const int lane  = tid & 63;
    const int wave  = tid >> 6;
    const int col16 = lane & 15;
    const int quad  = lane >> 4;
    const int wm = wave >> 2;              // 0..1  (M half, 128 rows)
    const int wn = wave & 3;               // 0..3  (N quarter, 48 cols)
    const int rowblk = blockIdx.y * 256;
    const int colblk = blockIdx.x * 192;

    const short* Ap = reinterpret_cast<const short*>(A);
    const short* Bp = reinterpret_cast<const short*>(Bm);

    // staging source mapping (inverse swizzle; constant per thread)
    const int o  = tid * 16;                         // byte off in 8KB unit
    const int s  = o ^ (((o >> 7) & 7) << 4);
    const int sr = s >> 7;                           // row 0..63 within unit
    const int sc = (s & 127) >> 1;                   // short col 0..63
    const int ldst = tid * 8;                        // dest short idx in unit

    // read-side swizzled k-offsets (shorts)
    const int mask = (col16 & 7) << 4;               // byte swizzle mask
    const int e0 = ((quad * 16)      ^ mask) >> 1;   // kk=0
    const int e1 = ((64 + quad * 16) ^ mask) >> 1;   // kk=1
    const int arow = (wm * 128 + col16) * 64;        // + m*1024
    const int brow = (wn * 48  + col16) * 64;        // + n*1024

    floatx4 acc[8][3] = {};

    auto STAGE_A = [&](int c, int u, int t) {
        const short* g = Ap + (size_t)(rowblk + u * 64 + sr) * K + t * 64 + sc;
        gload_lds16(g, &lds[c * 16384 + u * 4096 + ldst]);
    };
    auto STAGE_B = [&](int c, int u, int t) {
        const short* g = Bp + (size_t)(colblk + u * 64 + sr) * K + t * 64 + sc;
        gload_lds16(g, &lds[32768 + c * 12288 + u * 4096 + ldst]);
    };

    // ---- prologue: tile0 complete (7) + tile1 A (4); keep A(1) in flight
    STAGE_A(0, 0, 0); STAGE_A(0, 1, 0); STAGE_A(0, 2, 0); STAGE_A(0, 3, 0);
    STAGE_B(0, 0, 0); STAGE_B(0, 1, 0); STAGE_B(0, 2, 0);
    STAGE_A(1, 0, 1); STAGE_A(1, 1, 1); STAGE_A(1, 2, 1); STAGE_A(1, 3, 1);
    asm volatile("s_waitcnt vmcnt(4)" ::: "memory");
    __builtin_amdgcn_sched_barrier(0);
    BAR_();

    for (int t = 0; t < NT; ++t) {
        const int cur = t & 1, nxt = cur ^ 1;
        const int Ab = cur * 16384;
        const int Bb = 32768 + cur * 12288;
        short8 af0[8], af1[8], bf0[3], bf1[3];

        // ---- phase 1: read A kk0 + B kk0; stage B(t+1)u0,u1; MFMA kk0 n0,n1
#pragma unroll
        for (int m = 0; m < 8; ++m)
            af0[m] = *reinterpret_cast<const short8*>(&lds[Ab + arow + m * 1024 + e0]);
#pragma unroll
        for (int n = 0; n < 3; ++n)
            bf0[n] = *reinterpret_cast<const short8*>(&lds[Bb + brow + n * 1024 + e0]);
        if (t + 1 < NT) { STAGE_B(nxt, 0, t + 1); STAGE_B(nxt, 1, t + 1); }
        BAR_();
        __builtin_amdgcn_s_setprio(1);
#pragma unroll
        for (int m = 0; m < 8; ++m) {
            acc[m][0] = MFMA_(af0[m], bf0[0], acc[m][0], 0, 0, 0);
            acc[m][1] = MFMA_(af0[m], bf0[1], acc[m][1], 0, 0, 0);
        }
        __builtin_amdgcn_s_setprio(0);
        DRAIN_();
        BAR_();

        // ---- phase 2: read A kk1 + B kk1 n0; stage B(t+1)u2;
        //               MFMA kk0 n2 + kk1 n0
#pragma unroll
        for (int m = 0; m < 8; ++m)
            af1[m] = *reinterpret_cast<const short8*>(&lds[Ab + arow + m * 1024 + e1]);
        bf1[0] = *reinterpret_cast<const short8*>(&lds[Bb + brow + e1]);
        if (t + 1 < NT) STAGE_B(nxt, 2, t + 1);
        BAR_();
        __builtin_amdgcn_s_setprio(1);
#pragma unroll
        for (int m = 0; m < 8; ++m) {
            acc[m][2] = MFMA_(af0[m], bf0[2], acc[m][2], 0, 0, 0);
            acc[m][0] = MFMA_(af1[m], bf1[0], acc[m][0], 0, 0, 0);
        }
        __builtin_amdgcn_s_setprio(0);
        DRAIN_();
        BAR_();

        // ---- phase 3: read B kk1 n1,n2; stage A(t+2)u0..3; counted vmcnt;
        //               MFMA kk1 n1,n2
        bf1[1] = *reinterpret_cast<const short8*>(&lds[Bb + brow + 1024 + e1]);
        bf1[2] = *reinterpret_cast<const short8*>(&lds[Bb + brow + 2048 + e1]);
        if (t + 2 < NT) {
            STAGE_A(cur, 0, t + 2); STAGE_A(cur, 1, t + 2);
            STAGE_A(cur, 2, t + 2); STAGE_A(cur, 3, t + 2);
        }
        if (t >= NT - 2) { asm volatile("s_waitcnt vmcnt(0)" ::: "memory"); }
        else             { asm volatile("s_waitcnt vmcnt(4)" ::: "memory"); }
        __builtin_amdgcn_sched_barrier(0);
        BAR_();
        __builtin_amdgcn_s_setprio(1);
#pragma unroll
        for (int m = 0; m < 8; ++m) {
            acc[m][1] = MFMA_(af1[m], bf1[1], acc[m][1], 0, 0, 0);
            acc[m][2] = MFMA_(af1[m], bf1[2], acc[m][2], 0, 0, 0);
        }
        __builtin_amdgcn_s_setprio(0);
        DRAIN_();
        BAR_();
    }

    // ---- epilogue ----
    if (blockIdx.x < 24) {
        // bf16 qkv tile: stage through LDS, store coalesced dwordx4.
        // All staging LDS reads drained at loop's final DRAIN+BAR.
        const int rb = wm * 128 + quad * 4;
        const int cb = wn * 48 + col16;
#pragma unroll
        for (int m = 0; m < 8; ++m)
#pragma unroll
            for (int n = 0; n < 3; ++n)
#pragma unroll
                for (int r = 0; r < 4; ++r)
                    lds[(rb + m * 16 + r) * CSTR + cb + n * 16] =
                        f2bfs(acc[m][n][r]);
        __syncthreads();
        const int row = tid >> 1;
        const int seg = tid & 1;
        const short* srcp = &lds[row * CSTR + seg * 96];
        short* dstp = reinterpret_cast<short*>(qkv_out)
                    + (size_t)(rowblk + row) * QKV_ + colblk + seg * 96;
#pragma unroll
        for (int j = 0; j < 12; ++j)
            *reinterpret_cast<short8*>(dstp + j * 8) =
                *reinterpret_cast<const short8*>(srcp + j * 8);
    } else {
        const int row0  = rowblk + wm * 128;
        const int col0g = colblk + wn * 48 - QKV_;
#pragma unroll
        for (int m = 0; m < 8; ++m)
#pragma unroll
            for (int n = 0; n < 3; ++n)
#pragma unroll
                for (int r = 0; r < 4; ++r) {
                    int row = row0 + m * 16 + quad * 4 + r;
                    int col = col0g + n * 16 + col16;
                    z_out[(size_t)row * DSSM_ + col] = acc[m][n][r] + b_z[col];
                }
    }
}

// =====================================================================
// NT GEMM, LDS-staged (m97 structure) — used for the output projection
// =====================================================================
template<int OUTMODE>
__global__ __launch_bounds__(256) void gemm_nt(
    const __hip_bfloat16* __restrict__ A,
    const __hip_bfloat16* __restrict__ Bm,
    void* __restrict__ Cv,
    const float* __restrict__ bias,
    int M, int N, int K)
{
    const int lane  = threadIdx.x & 63;
    const int wave  = threadIdx.x >> 6;
    const int col16 = lane & 15;
    const int quad  = lane >> 4;
    const int wr    = wave >> 1;
    const int wc    = wave & 1;
    const int rowblk = blockIdx.y * 128;
    const int colblk = blockIdx.x * 128;

    const short* Ap = reinterpret_cast<const short*>(A);
    const short* Bp = reinterpret_cast<const short*>(Bm);

    __shared__ alignas(16) short As[128 * 32];
    __shared__ alignas(16) short Bs[128 * 32];

    const int srow = lane >> 2;
    const int scol = (lane & 3) * 8;

    floatx4 acc[4][4] = {};

    for (int k0 = 0; k0 < K; k0 += 32) {
#pragma unroll
        for (int s2 = 0; s2 < 2; ++s2) {
            const int seg = wave * 2 + s2;
            gload_lds16(Ap + (size_t)(rowblk + seg * 16 + srow) * K + k0 + scol,
                        &As[seg * 512]);
            gload_lds16(Bp + (size_t)(colblk + seg * 16 + srow) * K + k0 + scol,
                        &Bs[seg * 512]);
        }
        __syncthreads();

        short8 af[4], bf[4];
#pragma unroll
        for (int t = 0; t < 4; ++t) {
            af[t] = *reinterpret_cast<const short8*>(
                &As[(wr * 64 + t * 16 + col16) * 32 + quad * 8]);
            bf[t] = *reinterpret_cast<const short8*>(
                &Bs[(wc * 64 + t * 16 + col16) * 32 + quad * 8]);
        }
#pragma unroll
        for (int mt = 0; mt < 4; ++mt)
#pragma unroll
            for (int nt = 0; nt < 4; ++nt)
                acc[mt][nt] = __builtin_amdgcn_mfma_f32_16x16x32_bf16(
                    af[mt], bf[nt], acc[mt][nt], 0, 0, 0);
        __syncthreads();
    }

    const int row0 = rowblk + wr * 64;
    const int col0 = colblk + wc * 64;
#pragma unroll
    for (int mt = 0; mt < 4; ++mt) {
#pragma unroll
        for (int nt = 0; nt < 4; ++nt) {
#pragma unroll
            for (int r = 0; r < 4; ++r) {
                int row = row0 + mt * 16 + quad * 4 + r;
                int col = col0 + nt * 16 + col16;
                float v = acc[mt][nt][r];
                if (OUTMODE == 1) v += bias[col];
                if (OUTMODE == 2)
                    ((__hip_bfloat16*)Cv)[(size_t)row * N + col] = __float2bfloat16(v);
                else
                    ((float*)Cv)[(size_t)row * N + col] = v;
            }
        }
    }
}

// =====================================================================
// depthwise causal conv (k=2) + SiLU -> q/k/v [B,NH,L,HD] bf16
// vectorized: 8 channels/thread (short8 in/out, 16B/lane)
// =====================================================================
__global__ void conv_silu_kernel(
    const __hip_bfloat16* __restrict__ raw,
    const float* __restrict__ conv_w,
    __hip_bfloat16* __restrict__ q,
    __hip_bfloat16* __restrict__ k,
    __hip_bfloat16* __restrict__ v)
{
    int idx8 = blockIdx.x * 256 + threadIdx.x;   // over B*L*QKV/8
    int c8 = (idx8 % (QKV_ / 8)) * 8;
    int ml = idx8 / (QKV_ / 8);
    int l  = ml % L_;
    int b  = ml / L_;

    const short* base = reinterpret_cast<const short*>(raw) + (size_t)ml * QKV_ + c8;
    short8 curv = *reinterpret_cast<const short8*>(base);
    short8 prevv = {};
    if (l > 0) prevv = *reinterpret_cast<const short8*>(base - QKV_);

    float4 w0 = *reinterpret_cast<const float4*>(conv_w + c8 * 2);
    float4 w1 = *reinterpret_cast<const float4*>(conv_w + c8 * 2 + 4);
    float4 w2 = *reinterpret_cast<const float4*>(conv_w + c8 * 2 + 8);
    float4 w3 = *reinterpret_cast<const float4*>(conv_w + c8 * 2 + 12);
    const float wa[16] = {w0.x, w0.y, w0.z, w0.w, w1.x, w1.y, w1.z, w1.w,
                          w2.x, w2.y, w2.z, w2.w, w3.x, w3.y, w3.z, w3.w};

    short8 outv;
#pragma unroll
    for (int j = 0; j < 8; ++j) {
        float u = bfs2f(prevv[j]) * wa[2 * j] + bfs2f(curv[j]) * wa[2 * j + 1];
        u = fmaxf(u, -80.f);
        outv[j] = f2bfs(u / (1.f + __expf(-u)));
    }

    int part = c8 / DSSM_;                // 8-ch group never crosses a part
    int cc   = c8 % DSSM_;
    int nh   = cc >> 6;
    int d    = cc & 63;                   // never crosses an nh (64%8==0)
    __hip_bfloat16* dst = (part == 0) ? q : ((part == 1) ? k : v);
    *reinterpret_cast<short8*>(
        reinterpret_cast<short*>(dst) + (((size_t)b * NH_ + nh) * L_ + l) * HD_ + d)
        = outv;
}

// =====================================================================
// dt projection v2 (fp32, LDS-staged x, register-held fragments)
// =====================================================================
__global__ __launch_bounds__(256) void dtproj_kernel(
    const float* __restrict__ x,        // [B*L, HID]
    const float* __restrict__ w_dt,     // [NH, HID]
    const float* __restrict__ dt_bias,  // [NH]
    const float* __restrict__ a_log,    // [NH]
    float* __restrict__ dt,             // [B*NH, L]
    float* __restrict__ dA)
{
    const int m0   = blockIdx.x * 8;
    const int tid  = threadIdx.x;
    const int wave = tid >> 6;
    const int lane = tid & 63;

    __shared__ float Xs[8][HID_];

    for (int t = tid; t < 8 * (HID_ / 4); t += 256) {
        int r = t / (HID_ / 4), c = (t % (HID_ / 4)) * 4;
        *reinterpret_cast<float4*>(&Xs[r][c]) =
            *reinterpret_cast<const float4*>(x + (size_t)(m0 + r) * HID_ + c);
    }
    __syncthreads();

    const int r0 = wave * 2;
    float4 xa[2][6];
#pragma unroll
    for (int rr = 0; rr < 2; ++rr)
#pragma unroll
        for (int it = 0; it < 6; ++it)
            xa[rr][it] = *reinterpret_cast<const float4*>(&Xs[r0 + rr][lane * 4 + it * 256]);

    for (int n = 0; n < NH_; ++n) {
        float s0 = 0.f, s1 = 0.f;
#pragma unroll
        for (int it = 0; it < 6; ++it) {
            float4 w = *reinterpret_cast<const float4*>(
                w_dt + (size_t)n * HID_ + lane * 4 + it * 256);
            s0 += xa[0][it].x * w.x + xa[0][it].y * w.y
                + xa[0][it].z * w.z + xa[0][it].w * w.w;
            s1 += xa[1][it].x * w.x + xa[1][it].y * w.y
                + xa[1][it].z * w.z + xa[1][it].w * w.w;
        }
#pragma unroll
        for (int off = 32; off; off >>= 1) {
            s0 += __shfl_xor(s0, off, 64);
            s1 += __shfl_xor(s1, off, 64);
        }
        if (lane == 0) {
            float Aval = -__expf(a_log[n]);
            float bias = dt_bias[n];
#pragma unroll
            for (int rr = 0; rr < 2; ++rr) {
                float vdt = (rr == 0 ? s0 : s1) + bias;
                vdt = (vdt > 20.f) ? vdt : log1pf(__expf(vdt));
                int m = m0 + r0 + rr;
                int b = m / L_, l = m % L_;
                size_t o = ((size_t)b * NH_ + n) * L_ + l;
                dt[o] = vdt;
                dA[o] = vdt * Aval;
            }
        }
    }
}

// =====================================================================
// cumsum over L per (b,nh)
// =====================================================================
__global__ void cumsum_kernel(const float* __restrict__ dA, float* __restrict__ cs)
{
    int bnh  = blockIdx.x;
    int lane = threadIdx.x;
    const float* src = dA + (size_t)bnh * L_;
    float* dst       = cs + (size_t)bnh * L_;

    float loc[16];
    float run = 0.f;
#pragma unroll
    for (int t = 0; t < 16; ++t) { run += src[lane * 16 + t]; loc[t] = run; }
    float tot = run;
    float sc = tot;
#pragma unroll
    for (int off = 1; off < 64; off <<= 1) {
        float o = __shfl_up(sc, off, 64);
        if (lane >= off) sc += o;
    }
    float offset = sc - tot;
#pragma unroll
    for (int t = 0; t < 16; ++t) dst[lane * 16 + t] = loc[t] + offset;
}

// =====================================================================
// V -> Vt transpose with dt folding
// =====================================================================
__global__ __launch_bounds__(256) void vdt_transpose_kernel(
    const __hip_bfloat16* __restrict__ v,   // [B,NH,L,HD]
    const float* __restrict__ dt,           // [B,NH,L]
    __hip_bfloat16* __restrict__ vt)        // [B,NH,HD,L] (dt-scaled)
{
    const int lt0 = blockIdx.x * 64;
    const int bnh = blockIdx.z * NH_ + blockIdx.y;
    const int tid = threadIdx.x;

    __shared__ short T[64][72];

    {
        int row = tid >> 2;
        int cc  = (tid & 3) * 16;
        const short* sp = reinterpret_cast<const short*>(v)
                        + ((size_t)bnh * L_ + lt0 + row) * HD_ + cc;
        float dtr = dt[(size_t)bnh * L_ + lt0 + row];
        short8 a = *reinterpret_cast<const short8*>(sp);
        short8 b = *reinterpret_cast<const short8*>(sp + 8);
#pragma unroll
        for (int j = 0; j < 8; ++j) {
            T[row][cc + j]     = f2bfs(bfs2f(a[j]) * dtr);
            T[row][cc + 8 + j] = f2bfs(bfs2f(b[j]) * dtr);
        }
    }
    __syncthreads();
    {
        int d  = tid >> 2;
        int lc = (tid & 3) * 16;
        short8 o0, o1;
#pragma unroll
        for (int j = 0; j < 8; ++j) {
            o0[j] = T[lc + j][d];
            o1[j] = T[lc + 8 + j][d];
        }
        short* dst = reinterpret_cast<short*>(vt)
                   + ((size_t)bnh * HD_ + d) * L_ + lt0 + lc;
        *reinterpret_cast<short8*>(dst)     = o0;
        *reinterpret_cast<short8*>(dst + 8) = o1;
    }
}

// =====================================================================
// quadratic SSD attention — one (i-tile, j-slice) per block.
// =====================================================================
__global__ __launch_bounds__(256) void attn_kernel(
    const __hip_bfloat16* __restrict__ q,   // [B,NH,L,HD]
    const __hip_bfloat16* __restrict__ k,   // [B,NH,L,HD]
    const __hip_bfloat16* __restrict__ vt,  // [B,NH,HD,L], dt-scaled
    const float* __restrict__ cs,           // [B,NH,L]
    float* __restrict__ p0,                 // [B,L,DSSM] partials
    float* __restrict__ p1,
    float* __restrict__ p2)
{
    const int pidx = blockIdx.x;            // 0..29
    const int it   = kIt[pidx];
    const int sl   = kS[pidx];
    const int nh   = blockIdx.y;
    const int b    = blockIdx.z;
    const int tid  = threadIdx.x;
    const int lane = tid & 63;
    const int wave = tid >> 6;
    const int col  = lane & 15;
    const int quad = lane >> 4;
    const int bnh  = b * NH_ + nh;
    const int iw0  = it * 64 + wave * 16;

    float* pout = (sl == 0) ? p0 : ((sl == 1) ? p1 : p2);

    const short* qp  = reinterpret_cast<const short*>(q);
    const short* kp  = reinterpret_cast<const short*>(k);
    const short* vtp = reinterpret_cast<const short*>(vt);

    __shared__ alignas(16) short Ks[4096];
    __shared__ alignas(16) short Ps[4 * 16 * 72];

    const short* qrow = qp + ((size_t)bnh * L_ + iw0 + col) * HD_;
    short8 aq0 = *reinterpret_cast<const short8*>(qrow + quad * 8);
    short8 aq1 = *reinterpret_cast<const short8*>(qrow + 32 + quad * 8);

    float csr[4];
#pragma unroll
    for (int r = 0; r < 4; ++r)
        csr[r] = cs[(size_t)bnh * L_ + iw0 + quad * 4 + r];

    floatx4 accO[4] = {};

    const int jt_end = min(sl * 6 + 5, it);
    for (int jt = sl * 6; jt <= jt_end; ++jt) {
        const int j0 = jt * 64;
        {
            const short* gk = kp + ((size_t)bnh * L_ + j0 + wave * 16 + (lane >> 2)) * HD_
                            + (lane & 3) * 8;
            gload_lds16(gk,      &Ks[wave * 512 + lane * 8]);
            gload_lds16(gk + 32, &Ks[2048 + wave * 512 + lane * 8]);
        }
        __syncthreads();

#pragma unroll
        for (int s = 0; s < 4; ++s) {
            int jsub = j0 + s * 16;
            if (jsub <= iw0 + 15) {
                short8 bk0 = *reinterpret_cast<const short8*>(
                    &Ks[(s * 16 + col) * 32 + quad * 8]);
                short8 bk1 = *reinterpret_cast<const short8*>(
                    &Ks[2048 + (s * 16 + col) * 32 + quad * 8]);
                floatx4 sc = {};
                sc = __builtin_amdgcn_mfma_f32_16x16x32_bf16(aq0, bk0, sc, 0, 0, 0);
                sc = __builtin_amdgcn_mfma_f32_16x16x32_bf16(aq1, bk1, sc, 0, 0, 0);
                int j = jsub + col;
                float csj = cs[(size_t)bnh * L_ + j];
#pragma unroll
                for (int r = 0; r < 4; ++r) {
                    int i = iw0 + quad * 4 + r;
                    float e = (j <= i) ? __expf(csr[r] - csj) : 0.f;
                    Ps[wave * 1152 + (quad * 4 + r) * 72 + s * 16 + col] =
                        f2bfs(sc[r] * e);
                }
            } else if (j0 + (s >> 1) * 32 <= iw0 + 15) {
#pragma unroll
                for (int r = 0; r < 4; ++r)
                    Ps[wave * 1152 + (quad * 4 + r) * 72 + s * 16 + col] = 0;
            }
        }

#pragma unroll
        for (int c = 0; c < 2; ++c) {
            if (j0 + c * 32 > iw0 + 15) continue;
            short8 pa = *reinterpret_cast<const short8*>(
                &Ps[wave * 1152 + col * 72 + c * 32 + quad * 8]);
#pragma unroll
            for (int nt = 0; nt < 4; ++nt) {
                short8 bv = *reinterpret_cast<const short8*>(
                    vtp + ((size_t)bnh * HD_ + nt * 16 + col) * L_
                        + j0 + c * 32 + quad * 8);
                accO[nt] = __builtin_amdgcn_mfma_f32_16x16x32_bf16(pa, bv, accO[nt], 0, 0, 0);
            }
        }
        __syncthreads();
    }

#pragma unroll
    for (int nt = 0; nt < 4; ++nt) {
#pragma unroll
        for (int r = 0; r < 4; ++r) {
            int i  = iw0 + quad * 4 + r;
            int dv = nt * 16 + col;
            pout[((size_t)b * L_ + i) * DSSM_ + nh * HD_ + dv] = accO[nt][r];
        }
    }
}

// =====================================================================
// gate: (p0[+p1][+p2] + v*D) * silu(z), then RMSNorm * rms_w  -> bf16
// vectorized: float4 / short4 (384 vec4 per row over 256 threads)
// =====================================================================
__global__ __launch_bounds__(256) void gate_rms_kernel(
    const float* __restrict__ p0,
    const float* __restrict__ p1,
    const float* __restrict__ p2,
    const float* __restrict__ z,
    const __hip_bfloat16* __restrict__ v,   // [B,NH,L,HD]
    const float* __restrict__ Dm,           // [NH,HD]
    const float* __restrict__ rms_w,
    __hip_bfloat16* __restrict__ yn)
{
    int m   = blockIdx.x;           // b*L + l
    int b   = m / L_;
    int l   = m % L_;
    int tid = threadIdx.x;
    size_t base = (size_t)m * DSSM_;
    const bool has1 = (l >= 384);
    const bool has2 = (l >= 768);

    floatx4 acc4[2] = {};
    float ss = 0.f;
#pragma unroll
    for (int t = 0; t < 2; ++t) {
        int i4 = t * 256 + tid;
        if (i4 < DSSM_ / 4) {
            int c  = i4 * 4;
            int nh = c >> 6, d = c & 63;
            floatx4 p = *reinterpret_cast<const floatx4*>(p0 + base + c);
            if (has1) p += *reinterpret_cast<const floatx4*>(p1 + base + c);
            if (has2) p += *reinterpret_cast<const floatx4*>(p2 + base + c);
            floatx4 dm = *reinterpret_cast<const floatx4*>(Dm + c);
            floatx4 zz = *reinterpret_cast<const floatx4*>(z + base + c);
            short4e vv = *reinterpret_cast<const short4e*>(
                reinterpret_cast<const short*>(v)
                + (((size_t)b * NH_ + nh) * L_ + l) * HD_ + d);
            floatx4 g;
#pragma unroll
            for (int j = 0; j < 4; ++j) {
                float yv = p[j] + bfs2f(vv[j]) * dm[j];
                float zv = fmaxf(zz[j], -80.f);
                float gv = yv * (zv / (1.f + __expf(-zv)));
                ss += gv * gv;
                g[j] = gv;
            }
            acc4[t] = g;
        }
    }
#pragma unroll
    for (int off = 32; off; off >>= 1) ss += __shfl_xor(ss, off, 64);
    __shared__ float red[4];
    if ((tid & 63) == 0) red[tid >> 6] = ss;
    __syncthreads();
    ss = red[0] + red[1] + red[2] + red[3];
    float r = rsqrtf(ss / (float)DSSM_ + 1e-6f);
#pragma unroll
    for (int t = 0; t < 2; ++t) {
        int i4 = t * 256 + tid;
        if (i4 < DSSM_ / 4) {
            int c = i4 * 4;
            floatx4 rw = *reinterpret_cast<const floatx4*>(rms_w + c);
            short4e o;
#pragma unroll
            for (int j = 0; j < 4; ++j)
                o[j] = f2bfs(acc4[t][j] * r * rw[j]);
            *reinterpret_cast<short4e*>(
                reinterpret_cast<short*>(yn) + base + c) = o;
        }
    }
}

// =====================================================================
extern "C" void kernel_launch(void* const* d_in, const int* in_sizes, int n_in,
                              void* d_out, int out_size, void* d_ws, size_t ws_size,
                              hipStream_t stream)
{
    const float* x       = (const float*)d_in[0];
    const float* w_qkv   = (const float*)d_in[1];
    const float* conv_w  = (const float*)d_in[2];
    const float* w_dt    = (const float*)d_in[3];
    const float* dt_bias = (const float*)d_in[4];
    const float* a_log   = (const float*)d_in[5];
    const float* Dm      = (const float*)d_in[6];
    const float* w_z     = (const float*)d_in[7];
    const float* b_z     = (const float*)d_in[8];
    const float* rms_w   = (const float*)d_in[9];
    const float* w_o     = (const float*)d_in[10];
    float* out = (float*)d_out;

    char* ws = (char*)d_ws;

    // ---- workspace layout (bytes), total 80,805,888 — overlap-audited ----
    // [0,         6291456)  : xb (cast->step1) -> vtb (5a->5b) -> yn (7->8)
    // [6291456,  11010048)  : wob (cast->step8, never reused)
    // [11010048, 23592960)  : zbuf fp32 (step1->step7)
    // [23592960, 61341696)  : wcat [23592960,42467328) + qkvb [42467328,61341696)
    //                         -> after step2 both dead -> p0|p1|p2 (3 x 12582912)
    // [61341696, 67633152)  : qb (step2->5b)
    // [67633152, 73924608)  : kb (step2->5b)
    // [73924608, 80216064)  : vb (step2->7)
    // [80216064, 80805888)  : dt | dA | cs
    __hip_bfloat16* xb    = (__hip_bfloat16*)(ws);
    __hip_bfloat16* wob   = (__hip_bfloat16*)(ws + 6291456);
    float*          zbuf  = (float*)(ws + 11010048);
    __hip_bfloat16* wcat  = (__hip_bfloat16*)(ws + 23592960);
    __hip_bfloat16* qkvb  = (__hip_bfloat16*)(ws + 42467328);
    __hip_bfloat16* qb    = (__hip_bfloat16*)(ws + 61341696);
    __hip_bfloat16* kb    = (__hip_bfloat16*)(ws + 67633152);
    __hip_bfloat16* vb    = (__hip_bfloat16*)(ws + 73924608);
    float* dt   = (float*)(ws + 80216064);
    float* dA   = (float*)(ws + 80412672);
    float* cs   = (float*)(ws + 80609280);
    // aliases (lifetimes disjoint per audit above)
    __hip_bfloat16* vtb = (__hip_bfloat16*)(ws);
    __hip_bfloat16* yn  = (__hip_bfloat16*)(ws);
    float* p0 = (float*)(ws + 23592960);
    float* p1 = (float*)(ws + 36175872);
    float* p2 = (float*)(ws + 48758784);

    // one-time: allow 114,688 B dynamic LDS for the 256x192 GEMM
    static bool attr_set = false;
    if (!attr_set) {
        (void)hipFuncSetAttribute(reinterpret_cast<const void*>(gemm_qkvz_256),
                                  hipFuncAttributeMaxDynamicSharedMemorySize,
                                  114688);
        attr_set = true;
    }

    // 0) fused casts: x->xb, w_qkv|w_z->wcat, w_o->wob
    cast_all_kernel<<<(CN0 + CN1 + CN2 + CN3) / 1024, 256, 0, stream>>>(
        x, w_qkv, w_z, w_o, xb, wcat, wob);

    // 1) fused qkv+z GEMM  [2048 x 6144], 256x192 tile, grid = 256 = 1/CU
    gemm_qkvz_256<<<dim3((QKV_ + DSSM_) / 192, M_ / 256), 512, 114688, stream>>>(
        xb, wcat, qkvb, zbuf, b_z);

    // 2) conv + silu -> q,k,v  (vectorized, 8 ch/thread)
    conv_silu_kernel<<<(B_ * L_ * QKV_ / 8) / 256, 256, 0, stream>>>(
        qkvb, conv_w, qb, kb, vb);

    // 3) dt / dA
    dtproj_kernel<<<M_ / 8, 256, 0, stream>>>(x, w_dt, dt_bias, a_log, dt, dA);

    // 4) cs = cumsum(dA)
    cumsum_kernel<<<B_ * NH_, 64, 0, stream>>>(dA, cs);

    // 5a) vt = transpose(v) * dt  (xb dead after step 1)
    vdt_transpose_kernel<<<dim3(L_ / 64, NH_, B_), 256, 0, stream>>>(vb, dt, vtb);

    // 5b) attention -> partials p0/p1/p2 (wcat+qkvb region dead)
    attn_kernel<<<dim3(30, NH_, B_), 256, 0, stream>>>(
        qb, kb, vtb, cs, p0, p1, p2);

    // 7) gate + RMSNorm -> yn (vtb slot; attn done)
    gate_rms_kernel<<<M_, 256, 0, stream>>>(p0, p1, p2, zbuf, vb, Dm, rms_w, yn);

    // 8) out = yn @ w_o^T
    gemm_nt<0><<<dim3(HID_ / 128, M_ / 128), 256, 0, stream>>>(
        yn, wob, (void*)out, nullptr, M_, HID_, DSSM_);
}

// Round 3
// 276.197 us; speedup vs baseline: 1.2462x; 1.1166x over previous
//
#include <hip/hip_runtime.h>
#include <hip/hip_bf16.h>
#include <math.h>

// ---- problem constants ----
#define B_ 2
#define L_ 1024
#define HID_ 1536
#define NH_ 24
#define HD_ 64
#define DSSM_ 1536
#define QKV_ 4608
#define M_ 2048

typedef __attribute__((ext_vector_type(8))) short short8;
typedef __attribute__((ext_vector_type(4))) short short4e;
typedef __attribute__((ext_vector_type(4))) float floatx4;

// async global -> LDS, 16 bytes per lane (global_load_lds_dwordx4)
__device__ __forceinline__ void gload_lds16(const short* g, short* l)
{
    __builtin_amdgcn_global_load_lds(
        (const __attribute__((address_space(1))) void*)g,
        (__attribute__((address_space(3))) void*)l,
        16, 0, 0);
}

__device__ __forceinline__ float bfs2f(short s)
{
    unsigned u = ((unsigned)(unsigned short)s) << 16;
    float f; __builtin_memcpy(&f, &u, 4); return f;
}
__device__ __forceinline__ short f2bfs(float f)
{
    __hip_bfloat16 h = __float2bfloat16(f);
    short s; __builtin_memcpy(&s, &h, 2); return s;
}

// (it, slice) lookup for the 30 slice-blocks per (b,nh)
__device__ const int kIt[30] = {0,1,2,3,4,5, 6,6, 7,7, 8,8, 9,9, 10,10, 11,11,
                                12,12,12, 13,13,13, 14,14,14, 15,15,15};
__device__ const int kS[30]  = {0,0,0,0,0,0, 0,1, 0,1, 0,1, 0,1, 0,1, 0,1,
                                0,1,2, 0,1,2, 0,1,2, 0,1,2};

// =====================================================================
// fused fp32 -> bf16 cast for x, w_qkv, w_z (contiguous into wcat), w_o
// =====================================================================
#define CN0 (M_ * HID_)       // 3,145,728
#define CN1 (QKV_ * HID_)     // 7,077,888
#define CN2 (DSSM_ * HID_)    // 2,359,296
#define CN3 (HID_ * DSSM_)    // 2,359,296
__global__ void cast_all_kernel(
    const float* __restrict__ x,  const float* __restrict__ wq,
    const float* __restrict__ wz, const float* __restrict__ wo,
    __hip_bfloat16* __restrict__ xb,
    __hip_bfloat16* __restrict__ wcat,   // [QKV+DSSM, HID]
    __hip_bfloat16* __restrict__ wob)
{
    int i = (blockIdx.x * 256 + threadIdx.x) * 4;
    const float* src; __hip_bfloat16* dst; int off;
    if (i < CN0)                   { src = x;  dst = xb;         off = i; }
    else if (i < CN0 + CN1)        { src = wq; dst = wcat;       off = i - CN0; }
    else if (i < CN0 + CN1 + CN2)  { src = wz; dst = wcat + CN1; off = i - CN0 - CN1; }
    else                           { src = wo; dst = wob;        off = i - CN0 - CN1 - CN2; }
    float4 f = *reinterpret_cast<const float4*>(src + off);
    dst[off]     = __float2bfloat16(f.x);
    dst[off + 1] = __float2bfloat16(f.y);
    dst[off + 2] = __float2bfloat16(f.z);
    dst[off + 3] = __float2bfloat16(f.w);
}

// =====================================================================
// Fused qkv+z GEMM, 256x192 tile / BK=64 / 8 waves, 3-phase counted-vmcnt
// pipeline.  grid 32x8 = 256 blocks = exactly 1/CU.
// __launch_bounds__(512,1): LDS (114KB) already caps at 1 block/CU; the
// previous ",2" forced a 128-VGPR budget (measured VGPR_Count=108) that
// made the allocator serialize fragment reads.  1 gives the full budget.
// =====================================================================
#define MFMA_ __builtin_amdgcn_mfma_f32_16x16x32_bf16
#define BAR_() __builtin_amdgcn_s_barrier()
#define DRAIN_() do { asm volatile("s_waitcnt lgkmcnt(0)" ::: "memory"); \
                      __builtin_amdgcn_sched_barrier(0); } while (0)

#define CSTR 200   // epilogue C-LDS row stride (shorts): 400B, 16B-aligned

__global__ __launch_bounds__(512, 1) void gemm_qkvz_256(
    const __hip_bfloat16* __restrict__ A,
    const __hip_bfloat16* __restrict__ Bm,
    __hip_bfloat16* __restrict__ qkv_out,
    float* __restrict__ z_out,
    const float* __restrict__ b_z)
{
    extern __shared__ short lds[];
    const int K  = HID_;
    const int NT = K / 64;                 // 24 K-tiles
    const int tid   = threadIdx.x;
    const int lane  = tid & 63;
    const int wave  = tid >> 6;
    const int col16 = lane & 15;
    const int quad  = lane >> 4;
    const int wm = wave >> 2;              // 0..1  (M half, 128 rows)
    const int wn = wave & 3;               // 0..3  (N quarter, 48 cols)
    const int rowblk = blockIdx.y * 256;
    const int colblk = blockIdx.x * 192;

    const short* Ap = reinterpret_cast<const short*>(A);
    const short* Bp = reinterpret_cast<const short*>(Bm);

    // staging source mapping (inverse swizzle; constant per thread)
    const int o  = tid * 16;                         // byte off in 8KB unit
    const int s  = o ^ (((o >> 7) & 7) << 4);
    const int sr = s >> 7;                           // row 0..63 within unit
    const int sc = (s & 127) >> 1;                   // short col 0..63
    const int ldst = tid * 8;                        // dest short idx in unit

    // read-side swizzled k-offsets (shorts)
    const int mask = (col16 & 7) << 4;               // byte swizzle mask
    const int e0 = ((quad * 16)      ^ mask) >> 1;   // kk=0
    const int e1 = ((64 + quad * 16) ^ mask) >> 1;   // kk=1
    const int arow = (wm * 128 + col16) * 64;        // + m*1024
    const int brow = (wn * 48  + col16) * 64;        // + n*1024

    floatx4 acc[8][3] = {};

    auto STAGE_A = [&](int c, int u, int t) {
        const short* g = Ap + (size_t)(rowblk + u * 64 + sr) * K + t * 64 + sc;
        gload_lds16(g, &lds[c * 16384 + u * 4096 + ldst]);
    };
    auto STAGE_B = [&](int c, int u, int t) {
        const short* g = Bp + (size_t)(colblk + u * 64 + sr) * K + t * 64 + sc;
        gload_lds16(g, &lds[32768 + c * 12288 + u * 4096 + ldst]);
    };

    // ---- prologue: tile0 complete (7) + tile1 A (4); keep A(1) in flight
    STAGE_A(0, 0, 0); STAGE_A(0, 1, 0); STAGE_A(0, 2, 0); STAGE_A(0, 3, 0);
    STAGE_B(0, 0, 0); STAGE_B(0, 1, 0); STAGE_B(0, 2, 0);
    STAGE_A(1, 0, 1); STAGE_A(1, 1, 1); STAGE_A(1, 2, 1); STAGE_A(1, 3, 1);
    asm volatile("s_waitcnt vmcnt(4)" ::: "memory");
    __builtin_amdgcn_sched_barrier(0);
    BAR_();

    for (int t = 0; t < NT; ++t) {
        const int cur = t & 1, nxt = cur ^ 1;
        const int Ab = cur * 16384;
        const int Bb = 32768 + cur * 12288;
        short8 af0[8], af1[8], bf0[3], bf1[3];

        // ---- phase 1: read A kk0 + B kk0; stage B(t+1)u0,u1; MFMA kk0 n0,n1
#pragma unroll
        for (int m = 0; m < 8; ++m)
            af0[m] = *reinterpret_cast<const short8*>(&lds[Ab + arow + m * 1024 + e0]);
#pragma unroll
        for (int n = 0; n < 3; ++n)
            bf0[n] = *reinterpret_cast<const short8*>(&lds[Bb + brow + n * 1024 + e0]);
        if (t + 1 < NT) { STAGE_B(nxt, 0, t + 1); STAGE_B(nxt, 1, t + 1); }
        BAR_();
        __builtin_amdgcn_s_setprio(1);
#pragma unroll
        for (int m = 0; m < 8; ++m) {
            acc[m][0] = MFMA_(af0[m], bf0[0], acc[m][0], 0, 0, 0);
            acc[m][1] = MFMA_(af0[m], bf0[1], acc[m][1], 0, 0, 0);
        }
        __builtin_amdgcn_s_setprio(0);
        DRAIN_();
        BAR_();

        // ---- phase 2: read A kk1 + B kk1 n0; stage B(t+1)u2;
        //               MFMA kk0 n2 + kk1 n0
#pragma unroll
        for (int m = 0; m < 8; ++m)
            af1[m] = *reinterpret_cast<const short8*>(&lds[Ab + arow + m * 1024 + e1]);
        bf1[0] = *reinterpret_cast<const short8*>(&lds[Bb + brow + e1]);
        if (t + 1 < NT) STAGE_B(nxt, 2, t + 1);
        BAR_();
        __builtin_amdgcn_s_setprio(1);
#pragma unroll
        for (int m = 0; m < 8; ++m) {
            acc[m][2] = MFMA_(af0[m], bf0[2], acc[m][2], 0, 0, 0);
            acc[m][0] = MFMA_(af1[m], bf1[0], acc[m][0], 0, 0, 0);
        }
        __builtin_amdgcn_s_setprio(0);
        DRAIN_();
        BAR_();

        // ---- phase 3: read B kk1 n1,n2; stage A(t+2)u0..3; counted vmcnt;
        //               MFMA kk1 n1,n2
        bf1[1] = *reinterpret_cast<const short8*>(&lds[Bb + brow + 1024 + e1]);
        bf1[2] = *reinterpret_cast<const short8*>(&lds[Bb + brow + 2048 + e1]);
        if (t + 2 < NT) {
            STAGE_A(cur, 0, t + 2); STAGE_A(cur, 1, t + 2);
            STAGE_A(cur, 2, t + 2); STAGE_A(cur, 3, t + 2);
        }
        if (t >= NT - 2) { asm volatile("s_waitcnt vmcnt(0)" ::: "memory"); }
        else             { asm volatile("s_waitcnt vmcnt(4)" ::: "memory"); }
        __builtin_amdgcn_sched_barrier(0);
        BAR_();
        __builtin_amdgcn_s_setprio(1);
#pragma unroll
        for (int m = 0; m < 8; ++m) {
            acc[m][1] = MFMA_(af1[m], bf1[1], acc[m][1], 0, 0, 0);
            acc[m][2] = MFMA_(af1[m], bf1[2], acc[m][2], 0, 0, 0);
        }
        __builtin_amdgcn_s_setprio(0);
        DRAIN_();
        BAR_();
    }

    // ---- epilogue ----
    if (blockIdx.x < 24) {
        // bf16 qkv tile: stage through LDS, store coalesced dwordx4.
        const int rb = wm * 128 + quad * 4;
        const int cb = wn * 48 + col16;
#pragma unroll
        for (int m = 0; m < 8; ++m)
#pragma unroll
            for (int n = 0; n < 3; ++n)
#pragma unroll
                for (int r = 0; r < 4; ++r)
                    lds[(rb + m * 16 + r) * CSTR + cb + n * 16] =
                        f2bfs(acc[m][n][r]);
        __syncthreads();
        const int row = tid >> 1;
        const int seg = tid & 1;
        const short* srcp = &lds[row * CSTR + seg * 96];
        short* dstp = reinterpret_cast<short*>(qkv_out)
                    + (size_t)(rowblk + row) * QKV_ + colblk + seg * 96;
#pragma unroll
        for (int j = 0; j < 12; ++j)
            *reinterpret_cast<short8*>(dstp + j * 8) =
                *reinterpret_cast<const short8*>(srcp + j * 8);
    } else {
        const int row0  = rowblk + wm * 128;
        const int col0g = colblk + wn * 48 - QKV_;
#pragma unroll
        for (int m = 0; m < 8; ++m)
#pragma unroll
            for (int n = 0; n < 3; ++n)
#pragma unroll
                for (int r = 0; r < 4; ++r) {
                    int row = row0 + m * 16 + quad * 4 + r;
                    int col = col0g + n * 16 + col16;
                    z_out[(size_t)row * DSSM_ + col] = acc[m][n][r] + b_z[col];
                }
    }
}

// =====================================================================
// NT GEMM, LDS-staged (m97 structure) — used for the output projection
// =====================================================================
template<int OUTMODE>
__global__ __launch_bounds__(256) void gemm_nt(
    const __hip_bfloat16* __restrict__ A,
    const __hip_bfloat16* __restrict__ Bm,
    void* __restrict__ Cv,
    const float* __restrict__ bias,
    int M, int N, int K)
{
    const int lane  = threadIdx.x & 63;
    const int wave  = threadIdx.x >> 6;
    const int col16 = lane & 15;
    const int quad  = lane >> 4;
    const int wr    = wave >> 1;
    const int wc    = wave & 1;
    const int rowblk = blockIdx.y * 128;
    const int colblk = blockIdx.x * 128;

    const short* Ap = reinterpret_cast<const short*>(A);
    const short* Bp = reinterpret_cast<const short*>(Bm);

    __shared__ alignas(16) short As[128 * 32];
    __shared__ alignas(16) short Bs[128 * 32];

    const int srow = lane >> 2;
    const int scol = (lane & 3) * 8;

    floatx4 acc[4][4] = {};

    for (int k0 = 0; k0 < K; k0 += 32) {
#pragma unroll
        for (int s2 = 0; s2 < 2; ++s2) {
            const int seg = wave * 2 + s2;
            gload_lds16(Ap + (size_t)(rowblk + seg * 16 + srow) * K + k0 + scol,
                        &As[seg * 512]);
            gload_lds16(Bp + (size_t)(colblk + seg * 16 + srow) * K + k0 + scol,
                        &Bs[seg * 512]);
        }
        __syncthreads();

        short8 af[4], bf[4];
#pragma unroll
        for (int t = 0; t < 4; ++t) {
            af[t] = *reinterpret_cast<const short8*>(
                &As[(wr * 64 + t * 16 + col16) * 32 + quad * 8]);
            bf[t] = *reinterpret_cast<const short8*>(
                &Bs[(wc * 64 + t * 16 + col16) * 32 + quad * 8]);
        }
#pragma unroll
        for (int mt = 0; mt < 4; ++mt)
#pragma unroll
            for (int nt = 0; nt < 4; ++nt)
                acc[mt][nt] = __builtin_amdgcn_mfma_f32_16x16x32_bf16(
                    af[mt], bf[nt], acc[mt][nt], 0, 0, 0);
        __syncthreads();
    }

    const int row0 = rowblk + wr * 64;
    const int col0 = colblk + wc * 64;
#pragma unroll
    for (int mt = 0; mt < 4; ++mt) {
#pragma unroll
        for (int nt = 0; nt < 4; ++nt) {
#pragma unroll
            for (int r = 0; r < 4; ++r) {
                int row = row0 + mt * 16 + quad * 4 + r;
                int col = col0 + nt * 16 + col16;
                float v = acc[mt][nt][r];
                if (OUTMODE == 1) v += bias[col];
                if (OUTMODE == 2)
                    ((__hip_bfloat16*)Cv)[(size_t)row * N + col] = __float2bfloat16(v);
                else
                    ((float*)Cv)[(size_t)row * N + col] = v;
            }
        }
    }
}

// =====================================================================
// depthwise causal conv (k=2) + SiLU -> q/k/v [B,NH,L,HD] bf16
// vectorized: 8 channels/thread (short8 in/out, 16B/lane)
// =====================================================================
__global__ void conv_silu_kernel(
    const __hip_bfloat16* __restrict__ raw,
    const float* __restrict__ conv_w,
    __hip_bfloat16* __restrict__ q,
    __hip_bfloat16* __restrict__ k,
    __hip_bfloat16* __restrict__ v)
{
    int idx8 = blockIdx.x * 256 + threadIdx.x;   // over B*L*QKV/8
    int c8 = (idx8 % (QKV_ / 8)) * 8;
    int ml = idx8 / (QKV_ / 8);
    int l  = ml % L_;
    int b  = ml / L_;

    const short* base = reinterpret_cast<const short*>(raw) + (size_t)ml * QKV_ + c8;
    short8 curv = *reinterpret_cast<const short8*>(base);
    short8 prevv = {};
    if (l > 0) prevv = *reinterpret_cast<const short8*>(base - QKV_);

    float4 w0 = *reinterpret_cast<const float4*>(conv_w + c8 * 2);
    float4 w1 = *reinterpret_cast<const float4*>(conv_w + c8 * 2 + 4);
    float4 w2 = *reinterpret_cast<const float4*>(conv_w + c8 * 2 + 8);
    float4 w3 = *reinterpret_cast<const float4*>(conv_w + c8 * 2 + 12);
    const float wa[16] = {w0.x, w0.y, w0.z, w0.w, w1.x, w1.y, w1.z, w1.w,
                          w2.x, w2.y, w2.z, w2.w, w3.x, w3.y, w3.z, w3.w};

    short8 outv;
#pragma unroll
    for (int j = 0; j < 8; ++j) {
        float u = bfs2f(prevv[j]) * wa[2 * j] + bfs2f(curv[j]) * wa[2 * j + 1];
        u = fmaxf(u, -80.f);
        outv[j] = f2bfs(u / (1.f + __expf(-u)));
    }

    int part = c8 / DSSM_;                // 8-ch group never crosses a part
    int cc   = c8 % DSSM_;
    int nh   = cc >> 6;
    int d    = cc & 63;                   // never crosses an nh (64%8==0)
    __hip_bfloat16* dst = (part == 0) ? q : ((part == 1) ? k : v);
    *reinterpret_cast<short8*>(
        reinterpret_cast<short*>(dst) + (((size_t)b * NH_ + nh) * L_ + l) * HD_ + d)
        = outv;
}

// =====================================================================
// dt projection v3: latency-optimized.  1 row-pair per wave, x frags in
// registers (coalesced float4), fully-unrolled 24-head loop with per-lane
// partials (no cross-lane ops inside), ONE butterfly reduce at the end,
// lanes 0..23 finalize.  No LDS, no __syncthreads.
// =====================================================================
__global__ __launch_bounds__(256) void dtproj_kernel(
    const float* __restrict__ x,        // [B*L, HID]
    const float* __restrict__ w_dt,     // [NH, HID]
    const float* __restrict__ dt_bias,  // [NH]
    const float* __restrict__ a_log,    // [NH]
    float* __restrict__ dt,             // [B*NH, L]
    float* __restrict__ dA)
{
    const int tid  = threadIdx.x;
    const int wave = tid >> 6;
    const int lane = tid & 63;
    const int m0   = blockIdx.x * 8 + wave * 2;   // rows m0, m0+1

    float4 xa[2][6];
#pragma unroll
    for (int rr = 0; rr < 2; ++rr)
#pragma unroll
        for (int j = 0; j < 6; ++j)
            xa[rr][j] = *reinterpret_cast<const float4*>(
                x + (size_t)(m0 + rr) * HID_ + lane * 4 + j * 256);

    float acc0[NH_], acc1[NH_];
#pragma unroll
    for (int n = 0; n < NH_; ++n) {
        float s0 = 0.f, s1 = 0.f;
#pragma unroll
        for (int j = 0; j < 6; ++j) {
            float4 w = *reinterpret_cast<const float4*>(
                w_dt + (size_t)n * HID_ + lane * 4 + j * 256);
            s0 += xa[0][j].x * w.x + xa[0][j].y * w.y
                + xa[0][j].z * w.z + xa[0][j].w * w.w;
            s1 += xa[1][j].x * w.x + xa[1][j].y * w.y
                + xa[1][j].z * w.z + xa[1][j].w * w.w;
        }
        acc0[n] = s0;
        acc1[n] = s1;
    }

    // butterfly reduce all 48 partials (6 levels, ILP across 48)
#pragma unroll
    for (int off = 32; off; off >>= 1) {
#pragma unroll
        for (int n = 0; n < NH_; ++n) {
            acc0[n] += __shfl_xor(acc0[n], off, 64);
            acc1[n] += __shfl_xor(acc1[n], off, 64);
        }
    }

    if (lane < NH_) {
        const int n = lane;
        float bias = dt_bias[n];
        float Aval = -__expf(a_log[n]);
        float v0 = acc0[n] + bias;
        float v1 = acc1[n] + bias;
        v0 = (v0 > 20.f) ? v0 : log1pf(__expf(v0));
        v1 = (v1 > 20.f) ? v1 : log1pf(__expf(v1));
        int b0 = m0 / L_, l0 = m0 % L_;
        size_t o0 = ((size_t)b0 * NH_ + n) * L_ + l0;
        dt[o0]     = v0;
        dA[o0]     = v0 * Aval;
        dt[o0 + 1] = v1;          // m0+1 same b (8-row blocks never span b)
        dA[o0 + 1] = v1 * Aval;
    }
}

// =====================================================================
// cumsum over L per (b,nh)
// =====================================================================
__global__ void cumsum_kernel(const float* __restrict__ dA, float* __restrict__ cs)
{
    int bnh  = blockIdx.x;
    int lane = threadIdx.x;
    const float* src = dA + (size_t)bnh * L_;
    float* dst       = cs + (size_t)bnh * L_;

    float loc[16];
    float run = 0.f;
#pragma unroll
    for (int t = 0; t < 16; ++t) { run += src[lane * 16 + t]; loc[t] = run; }
    float tot = run;
    float sc = tot;
#pragma unroll
    for (int off = 1; off < 64; off <<= 1) {
        float o = __shfl_up(sc, off, 64);
        if (lane >= off) sc += o;
    }
    float offset = sc - tot;
#pragma unroll
    for (int t = 0; t < 16; ++t) dst[lane * 16 + t] = loc[t] + offset;
}

// =====================================================================
// V -> Vt transpose with dt folding
// =====================================================================
__global__ __launch_bounds__(256) void vdt_transpose_kernel(
    const __hip_bfloat16* __restrict__ v,   // [B,NH,L,HD]
    const float* __restrict__ dt,           // [B,NH,L]
    __hip_bfloat16* __restrict__ vt)        // [B,NH,HD,L] (dt-scaled)
{
    const int lt0 = blockIdx.x * 64;
    const int bnh = blockIdx.z * NH_ + blockIdx.y;
    const int tid = threadIdx.x;

    __shared__ short T[64][72];

    {
        int row = tid >> 2;
        int cc  = (tid & 3) * 16;
        const short* sp = reinterpret_cast<const short*>(v)
                        + ((size_t)bnh * L_ + lt0 + row) * HD_ + cc;
        float dtr = dt[(size_t)bnh * L_ + lt0 + row];
        short8 a = *reinterpret_cast<const short8*>(sp);
        short8 b = *reinterpret_cast<const short8*>(sp + 8);
#pragma unroll
        for (int j = 0; j < 8; ++j) {
            T[row][cc + j]     = f2bfs(bfs2f(a[j]) * dtr);
            T[row][cc + 8 + j] = f2bfs(bfs2f(b[j]) * dtr);
        }
    }
    __syncthreads();
    {
        int d  = tid >> 2;
        int lc = (tid & 3) * 16;
        short8 o0, o1;
#pragma unroll
        for (int j = 0; j < 8; ++j) {
            o0[j] = T[lc + j][d];
            o1[j] = T[lc + 8 + j][d];
        }
        short* dst = reinterpret_cast<short*>(vt)
                   + ((size_t)bnh * HD_ + d) * L_ + lt0 + lc;
        *reinterpret_cast<short8*>(dst)     = o0;
        *reinterpret_cast<short8*>(dst + 8) = o1;
    }
}

// =====================================================================
// quadratic SSD attention — one (i-tile, j-slice) per block.
// =====================================================================
__global__ __launch_bounds__(256) void attn_kernel(
    const __hip_bfloat16* __restrict__ q,   // [B,NH,L,HD]
    const __hip_bfloat16* __restrict__ k,   // [B,NH,L,HD]
    const __hip_bfloat16* __restrict__ vt,  // [B,NH,HD,L], dt-scaled
    const float* __restrict__ cs,           // [B,NH,L]
    float* __restrict__ p0,                 // [B,L,DSSM] partials
    float* __restrict__ p1,
    float* __restrict__ p2)
{
    const int pidx = blockIdx.x;            // 0..29
    const int it   = kIt[pidx];
    const int sl   = kS[pidx];
    const int nh   = blockIdx.y;
    const int b    = blockIdx.z;
    const int tid  = threadIdx.x;
    const int lane = tid & 63;
    const int wave = tid >> 6;
    const int col  = lane & 15;
    const int quad = lane >> 4;
    const int bnh  = b * NH_ + nh;
    const int iw0  = it * 64 + wave * 16;

    float* pout = (sl == 0) ? p0 : ((sl == 1) ? p1 : p2);

    const short* qp  = reinterpret_cast<const short*>(q);
    const short* kp  = reinterpret_cast<const short*>(k);
    const short* vtp = reinterpret_cast<const short*>(vt);

    __shared__ alignas(16) short Ks[4096];
    __shared__ alignas(16) short Ps[4 * 16 * 72];

    const short* qrow = qp + ((size_t)bnh * L_ + iw0 + col) * HD_;
    short8 aq0 = *reinterpret_cast<const short8*>(qrow + quad * 8);
    short8 aq1 = *reinterpret_cast<const short8*>(qrow + 32 + quad * 8);

    float csr[4];
#pragma unroll
    for (int r = 0; r < 4; ++r)
        csr[r] = cs[(size_t)bnh * L_ + iw0 + quad * 4 + r];

    floatx4 accO[4] = {};

    const int jt_end = min(sl * 6 + 5, it);
    for (int jt = sl * 6; jt <= jt_end; ++jt) {
        const int j0 = jt * 64;
        {
            const short* gk = kp + ((size_t)bnh * L_ + j0 + wave * 16 + (lane >> 2)) * HD_
                            + (lane & 3) * 8;
            gload_lds16(gk,      &Ks[wave * 512 + lane * 8]);
            gload_lds16(gk + 32, &Ks[2048 + wave * 512 + lane * 8]);
        }
        __syncthreads();

#pragma unroll
        for (int s = 0; s < 4; ++s) {
            int jsub = j0 + s * 16;
            if (jsub <= iw0 + 15) {
                short8 bk0 = *reinterpret_cast<const short8*>(
                    &Ks[(s * 16 + col) * 32 + quad * 8]);
                short8 bk1 = *reinterpret_cast<const short8*>(
                    &Ks[2048 + (s * 16 + col) * 32 + quad * 8]);
                floatx4 sc = {};
                sc = __builtin_amdgcn_mfma_f32_16x16x32_bf16(aq0, bk0, sc, 0, 0, 0);
                sc = __builtin_amdgcn_mfma_f32_16x16x32_bf16(aq1, bk1, sc, 0, 0, 0);
                int j = jsub + col;
                float csj = cs[(size_t)bnh * L_ + j];
#pragma unroll
                for (int r = 0; r < 4; ++r) {
                    int i = iw0 + quad * 4 + r;
                    float e = (j <= i) ? __expf(csr[r] - csj) : 0.f;
                    Ps[wave * 1152 + (quad * 4 + r) * 72 + s * 16 + col] =
                        f2bfs(sc[r] * e);
                }
            } else if (j0 + (s >> 1) * 32 <= iw0 + 15) {
#pragma unroll
                for (int r = 0; r < 4; ++r)
                    Ps[wave * 1152 + (quad * 4 + r) * 72 + s * 16 + col] = 0;
            }
        }

#pragma unroll
        for (int c = 0; c < 2; ++c) {
            if (j0 + c * 32 > iw0 + 15) continue;
            short8 pa = *reinterpret_cast<const short8*>(
                &Ps[wave * 1152 + col * 72 + c * 32 + quad * 8]);
#pragma unroll
            for (int nt = 0; nt < 4; ++nt) {
                short8 bv = *reinterpret_cast<const short8*>(
                    vtp + ((size_t)bnh * HD_ + nt * 16 + col) * L_
                        + j0 + c * 32 + quad * 8);
                accO[nt] = __builtin_amdgcn_mfma_f32_16x16x32_bf16(pa, bv, accO[nt], 0, 0, 0);
            }
        }
        __syncthreads();
    }

#pragma unroll
    for (int nt = 0; nt < 4; ++nt) {
#pragma unroll
        for (int r = 0; r < 4; ++r) {
            int i  = iw0 + quad * 4 + r;
            int dv = nt * 16 + col;
            pout[((size_t)b * L_ + i) * DSSM_ + nh * HD_ + dv] = accO[nt][r];
        }
    }
}

// =====================================================================
// gate: (p0[+p1][+p2] + v*D) * silu(z), then RMSNorm * rms_w  -> bf16
// vectorized: float4 / short4 (384 vec4 per row over 256 threads)
// =====================================================================
__global__ __launch_bounds__(256) void gate_rms_kernel(
    const float* __restrict__ p0,
    const float* __restrict__ p1,
    const float* __restrict__ p2,
    const float* __restrict__ z,
    const __hip_bfloat16* __restrict__ v,   // [B,NH,L,HD]
    const float* __restrict__ Dm,           // [NH,HD]
    const float* __restrict__ rms_w,
    __hip_bfloat16* __restrict__ yn)
{
    int m   = blockIdx.x;           // b*L + l
    int b   = m / L_;
    int l   = m % L_;
    int tid = threadIdx.x;
    size_t base = (size_t)m * DSSM_;
    const bool has1 = (l >= 384);
    const bool has2 = (l >= 768);

    floatx4 acc4[2] = {};
    float ss = 0.f;
#pragma unroll
    for (int t = 0; t < 2; ++t) {
        int i4 = t * 256 + tid;
        if (i4 < DSSM_ / 4) {
            int c  = i4 * 4;
            int nh = c >> 6, d = c & 63;
            floatx4 p = *reinterpret_cast<const floatx4*>(p0 + base + c);
            if (has1) p += *reinterpret_cast<const floatx4*>(p1 + base + c);
            if (has2) p += *reinterpret_cast<const floatx4*>(p2 + base + c);
            floatx4 dm = *reinterpret_cast<const floatx4*>(Dm + c);
            floatx4 zz = *reinterpret_cast<const floatx4*>(z + base + c);
            short4e vv = *reinterpret_cast<const short4e*>(
                reinterpret_cast<const short*>(v)
                + (((size_t)b * NH_ + nh) * L_ + l) * HD_ + d);
            floatx4 g;
#pragma unroll
            for (int j = 0; j < 4; ++j) {
                float yv = p[j] + bfs2f(vv[j]) * dm[j];
                float zv = fmaxf(zz[j], -80.f);
                float gv = yv * (zv / (1.f + __expf(-zv)));
                ss += gv * gv;
                g[j] = gv;
            }
            acc4[t] = g;
        }
    }
#pragma unroll
    for (int off = 32; off; off >>= 1) ss += __shfl_xor(ss, off, 64);
    __shared__ float red[4];
    if ((tid & 63) == 0) red[tid >> 6] = ss;
    __syncthreads();
    ss = red[0] + red[1] + red[2] + red[3];
    float r = rsqrtf(ss / (float)DSSM_ + 1e-6f);
#pragma unroll
    for (int t = 0; t < 2; ++t) {
        int i4 = t * 256 + tid;
        if (i4 < DSSM_ / 4) {
            int c = i4 * 4;
            floatx4 rw = *reinterpret_cast<const floatx4*>(rms_w + c);
            short4e o;
#pragma unroll
            for (int j = 0; j < 4; ++j)
                o[j] = f2bfs(acc4[t][j] * r * rw[j]);
            *reinterpret_cast<short4e*>(
                reinterpret_cast<short*>(yn) + base + c) = o;
        }
    }
}

// =====================================================================
extern "C" void kernel_launch(void* const* d_in, const int* in_sizes, int n_in,
                              void* d_out, int out_size, void* d_ws, size_t ws_size,
                              hipStream_t stream)
{
    const float* x       = (const float*)d_in[0];
    const float* w_qkv   = (const float*)d_in[1];
    const float* conv_w  = (const float*)d_in[2];
    const float* w_dt    = (const float*)d_in[3];
    const float* dt_bias = (const float*)d_in[4];
    const float* a_log   = (const float*)d_in[5];
    const float* Dm      = (const float*)d_in[6];
    const float* w_z     = (const float*)d_in[7];
    const float* b_z     = (const float*)d_in[8];
    const float* rms_w   = (const float*)d_in[9];
    const float* w_o     = (const float*)d_in[10];
    float* out = (float*)d_out;

    char* ws = (char*)d_ws;

    // ---- workspace layout (bytes), total 80,805,888 — overlap-audited ----
    // [0,         6291456)  : xb (cast->step1) -> vtb (5a->5b) -> yn (7->8)
    // [6291456,  11010048)  : wob (cast->step8, never reused)
    // [11010048, 23592960)  : zbuf fp32 (step1->step7)
    // [23592960, 61341696)  : wcat [23592960,42467328) + qkvb [42467328,61341696)
    //                         -> after step2 both dead -> p0|p1|p2 (3 x 12582912)
    // [61341696, 67633152)  : qb (step2->5b)
    // [67633152, 73924608)  : kb (step2->5b)
    // [73924608, 80216064)  : vb (step2->7)
    // [80216064, 80805888)  : dt | dA | cs
    __hip_bfloat16* xb    = (__hip_bfloat16*)(ws);
    __hip_bfloat16* wob   = (__hip_bfloat16*)(ws + 6291456);
    float*          zbuf  = (float*)(ws + 11010048);
    __hip_bfloat16* wcat  = (__hip_bfloat16*)(ws + 23592960);
    __hip_bfloat16* qkvb  = (__hip_bfloat16*)(ws + 42467328);
    __hip_bfloat16* qb    = (__hip_bfloat16*)(ws + 61341696);
    __hip_bfloat16* kb    = (__hip_bfloat16*)(ws + 67633152);
    __hip_bfloat16* vb    = (__hip_bfloat16*)(ws + 73924608);
    float* dt   = (float*)(ws + 80216064);
    float* dA   = (float*)(ws + 80412672);
    float* cs   = (float*)(ws + 80609280);
    // aliases (lifetimes disjoint per audit above)
    __hip_bfloat16* vtb = (__hip_bfloat16*)(ws);
    __hip_bfloat16* yn  = (__hip_bfloat16*)(ws);
    float* p0 = (float*)(ws + 23592960);
    float* p1 = (float*)(ws + 36175872);
    float* p2 = (float*)(ws + 48758784);

    // one-time: allow 114,688 B dynamic LDS for the 256x192 GEMM
    static bool attr_set = false;
    if (!attr_set) {
        (void)hipFuncSetAttribute(reinterpret_cast<const void*>(gemm_qkvz_256),
                                  hipFuncAttributeMaxDynamicSharedMemorySize,
                                  114688);
        attr_set = true;
    }

    // 0) fused casts: x->xb, w_qkv|w_z->wcat, w_o->wob
    cast_all_kernel<<<(CN0 + CN1 + CN2 + CN3) / 1024, 256, 0, stream>>>(
        x, w_qkv, w_z, w_o, xb, wcat, wob);

    // 1) fused qkv+z GEMM  [2048 x 6144], 256x192 tile, grid = 256 = 1/CU
    gemm_qkvz_256<<<dim3((QKV_ + DSSM_) / 192, M_ / 256), 512, 114688, stream>>>(
        xb, wcat, qkvb, zbuf, b_z);

    // 2) conv + silu -> q,k,v  (vectorized, 8 ch/thread)
    conv_silu_kernel<<<(B_ * L_ * QKV_ / 8) / 256, 256, 0, stream>>>(
        qkvb, conv_w, qb, kb, vb);

    // 3) dt / dA  (v3: register frags, single butterfly)
    dtproj_kernel<<<M_ / 8, 256, 0, stream>>>(x, w_dt, dt_bias, a_log, dt, dA);

    // 4) cs = cumsum(dA)
    cumsum_kernel<<<B_ * NH_, 64, 0, stream>>>(dA, cs);

    // 5a) vt = transpose(v) * dt  (xb dead after step 1)
    vdt_transpose_kernel<<<dim3(L_ / 64, NH_, B_), 256, 0, stream>>>(vb, dt, vtb);

    // 5b) attention -> partials p0/p1/p2 (wcat+qkvb region dead)
    attn_kernel<<<dim3(30, NH_, B_), 256, 0, stream>>>(
        qb, kb, vtb, cs, p0, p1, p2);

    // 7) gate + RMSNorm -> yn (vtb slot; attn done)
    gate_rms_kernel<<<M_, 256, 0, stream>>>(p0, p1, p2, zbuf, vb, Dm, rms_w, yn);

    // 8) out = yn @ w_o^T
    gemm_nt<0><<<dim3(HID_ / 128, M_ / 128), 256, 0, stream>>>(
        yn, wob, (void*)out, nullptr, M_, HID_, DSSM_);
}